// Round 8
// baseline (5034.543 us; speedup 1.0000x reference)
//
#include <hip/hip_runtime.h>
#include <hip/hip_fp16.h>

typedef __attribute__((ext_vector_type(8))) short short8;
typedef __attribute__((ext_vector_type(4))) float floatx4;

#define DEVFN static __device__ __forceinline__

DEVFN short f2h(float v) { return __half_as_short(__float2half(v)); }

DEVFN void gload16(const void* g, void* l) {
  void* gnc = const_cast<void*>(g);
  __builtin_amdgcn_global_load_lds(
      (__attribute__((address_space(1))) void*)gnc,
      (__attribute__((address_space(3))) void*)l, 16, 0, 0);
}

// flag set for (role, s, gy): 32 cells, one per u-tile block
DEVFN unsigned* fset(unsigned* f, int role, int s, int gy) {
  return f + ((((role * 79) + s) * 8 + gy) << 5);
}

// Persistent dataflow kernel: 79 sequential steps per role, point-to-point
// flag sync:  L1(s) <- {L0(s), L1(s-1)};  L0(s) <- {L0(s-1), L1(s-2)}.
// K-loop: K-step=32, 4 LDS buffers, prefetch depth 3, counted vmcnt
// (never 0 mid-loop) + raw s_barrier  [T3/T4, m201/m218 pattern].
// Grid (64,8): bx<32 -> L0 (u-tile bx), bx>=32 -> L1 (u-tile bx-32).
__global__ __launch_bounds__(256, 2) void pers_kernel(
    short* xe0, short* xe1, short* xd0, short* xd1,
    const short* wc_e0, const short* wc_e1, const short* wc_d0, const short* wc_d1,
    const float* eb0, const float* eb1, const float* db0, const float* db1,
    const short* embe, const short* embd,
    const int* __restrict__ src, const int* __restrict__ tgt,
    short* dh1, unsigned* flags) {
  __shared__ short smem[32768];  // 4 buffers x (A 128x32 | W 128x32) fp16 = 64 KB
  const int tid = threadIdx.x;
  const int lane = tid & 63;
  const int wv = tid >> 6;   // 0..3
  const int wm = wv >> 1;    // 64-row group
  const int wu = wv & 1;     // 16-unit group
  const int l15 = lane & 15;
  const int l4 = lane >> 4;
  const int bx = blockIdx.x;
  const int role1 = bx >> 5;
  const int ut = bx & 31;
  const int u0 = ut * 32;
  const int gy = blockIdx.y;
  const int m0 = gy * 128;
  const int srow = lane >> 2;                              // 0..15
  const int sswz = ((lane & 3) * 16) ^ ((srow & 3) << 4);  // src-side LDS swizzle
  const long SL0 = 1024l * 1280, SL1 = 1024l * 2048;

  float cst[16];
#pragma unroll
  for (int i = 0; i < 16; ++i) cst[i] = 0.f;

  for (int s = 0; s < 79; ++s) {
    // ---- dependency wait (wave-0 lanes poll producer cells) ----
    unsigned* WA = nullptr;
    unsigned* WB = nullptr;
    if (!role1) {
      if (s >= 1) WA = fset(flags, 0, s - 1, gy);
      if (s >= 2) WB = fset(flags, 1, s - 2, gy);
    } else {
      WA = fset(flags, 0, s, gy);
      if (s >= 1) WB = fset(flags, 1, s - 1, gy);
    }
    if (WA || WB) {
      if (tid < 64) {
        unsigned* p = (tid < 32) ? (WA ? WA + tid : nullptr)
                                 : (WB ? WB + (tid - 32) : nullptr);
        if (p) {
          while (__hip_atomic_load(p, __ATOMIC_RELAXED,
                                   __HIP_MEMORY_SCOPE_AGENT) == 0u)
            __builtin_amdgcn_s_sleep(1);
          (void)__hip_atomic_load(p, __ATOMIC_ACQUIRE, __HIP_MEMORY_SCOPE_AGENT);
        }
      }
      __syncthreads();
    }

    // ---- step params ----
    const int enc = (s < 32) ? 1 : 0;
    const int t = enc ? s : s - 32;          // dec t = 0..46
    const int cur = t & 1, nxt = cur ^ 1;
    const short* A; const short* Wt; const float* bs; int ktot;
    short *d1 = nullptr, *d2 = nullptr, *d3 = nullptr, *xq = nullptr;
    int s1 = 0, o1 = 0, xs = 0;
    const short* xe = nullptr; const int* tk = nullptr;
    if (!role1) {
      if (enc) {
        A = xe0 + cur * SL0; Wt = wc_e0; bs = eb0; ktot = 1280;
        d2 = xe1 + cur * SL1;                 // hs0[t] -> enc L1 input (s=2048,o=0)
        s1 = 1280; o1 = 256; xs = 1280;
        if (t < 31) { d1 = xe0 + nxt * SL0; xq = d1; xe = embe; tk = src + (t + 1) * 1024; }
        else        { d1 = xd0;             xq = xd0; xe = embd; tk = tgt; }
      } else {
        A = xd0 + cur * SL0; Wt = wc_d0; bs = db0; ktot = 1280;
        d1 = xd0 + nxt * SL0; s1 = 1280; o1 = 256;
        d2 = xd1 + cur * SL1;                 // dh0 -> dec L1 input
        if (t < 46) { xq = xd0 + nxt * SL0; xs = 1280; xe = embd; tk = tgt + (t + 1) * 1024; }
      }
    } else {
      if (enc) {
        A = xe1 + cur * SL1; Wt = wc_e1; bs = eb1; ktot = 2048;
        d1 = (t < 31) ? (xe1 + nxt * SL1) : xd1; s1 = 2048; o1 = 1024;
      } else {
        A = xd1 + cur * SL1; Wt = wc_d1; bs = db1; ktot = 2048;
        d1 = xd1 + nxt * SL1; s1 = 2048; o1 = 1024;
        d3 = dh1 + (long)t * 1024 * 1024;     // archive dh1[t] (s=1024,o=0)
      }
    }

    // ---- GEMM: z = A @ W^T; deep-pipelined staging ----
    floatx4 acc[4][4];
#pragma unroll
    for (int g = 0; g < 4; ++g)
#pragma unroll
      for (int mi = 0; mi < 4; ++mi) acc[g][mi] = (floatx4){0.f, 0.f, 0.f, 0.f};

    const char* Ab = (const char*)A;
    const char* Wb = (const char*)Wt;
    const long kbytes = (long)ktot * 2;
    const int nkb = ktot >> 5;  // K=32 sub-tiles

    auto stage = [&](int kb, int bufi) {
      const long kboff = (long)kb * 64;
      short* sb = smem + bufi * 8192;
#pragma unroll
      for (int ci = 0; ci < 4; ++ci) {
        const int c = wv * 4 + ci;
        if (c < 8) {  // A: 16 rows per chunk
          const int row = m0 + c * 16 + srow;
          gload16(Ab + (long)row * kbytes + kboff + sswz, sb + c * 512);
        } else {      // W: 128 tile-rows = 4 gates x 32 units
          const int wr = (c - 8) * 16 + srow;
          const int wrow = (wr >> 5) * 1024 + u0 + (wr & 31);
          gload16(Wb + (long)wrow * kbytes + kboff + sswz, sb + 4096 + (c - 8) * 512);
        }
      }
    };

    // isolate vmcnt from prior-step stores / flag polls
    asm volatile("s_waitcnt vmcnt(0)" ::: "memory");
    stage(0, 0);
    stage(1, 1);
    stage(2, 2);
    for (int kb = 0; kb < nkb; ++kb) {
      if (kb + 2 < nkb)       asm volatile("s_waitcnt vmcnt(8)" ::: "memory");
      else if (kb + 1 < nkb)  asm volatile("s_waitcnt vmcnt(4)" ::: "memory");
      else                    asm volatile("s_waitcnt vmcnt(0)" ::: "memory");
      __builtin_amdgcn_sched_barrier(0);
      __builtin_amdgcn_s_barrier();        // all waves: buf[kb] ready
      __builtin_amdgcn_sched_barrier(0);
      if (kb + 3 < nkb) stage(kb + 3, (kb + 3) & 3);  // WAR-safe (see header)
      __builtin_amdgcn_sched_barrier(0);
      const short* sb = smem + (kb & 3) * 8192;
      short8 fa[4];
      short8 fb[4];
#pragma unroll
      for (int mi = 0; mi < 4; ++mi) {
        const int r = wm * 64 + mi * 16 + l15;
        fa[mi] = *(const short8*)(sb + r * 32 + ((l4 * 8) ^ ((r & 3) << 3)));
      }
#pragma unroll
      for (int g = 0; g < 4; ++g) {
        const int r = g * 32 + wu * 16 + l15;
        fb[g] = *(const short8*)(sb + 4096 + r * 32 + ((l4 * 8) ^ ((r & 3) << 3)));
      }
#pragma unroll
      for (int g = 0; g < 4; ++g)
#pragma unroll
        for (int mi = 0; mi < 4; ++mi)
          asm volatile("v_mfma_f32_16x16x32_f16 %0, %1, %2, %0"
                       : "+v"(acc[g][mi])
                       : "v"(fa[mi]), "v"(fb[g]));
    }
    __syncthreads();  // all LDS reads retired before ht overwrites buf0
    asm volatile("s_nop 7\ns_nop 7\ns_nop 7");  // MFMA -> VALU hazard guard

    // ---- LSTM cell (c in regs) -> h into LDS transpose tile ----
    const int u = u0 + wu * 16 + l15;
    const float bi = bs[u];
    const float bf_ = bs[1024 + u];
    const float bg = bs[2048 + u];
    const float bo = bs[3072 + u];
    short* ht = smem;  // [128][40] fp16, overlays buf0/buf1
    const int uloc = wu * 16 + l15;
#pragma unroll
    for (int mi = 0; mi < 4; ++mi) {
#pragma unroll
      for (int j = 0; j < 4; ++j) {
        const float zi = acc[0][mi][j] + bi;
        const float zf = acc[1][mi][j] + bf_;
        const float zg = acc[2][mi][j] + bg;
        const float zo = acc[3][mi][j] + bo;
        const float gi = 1.f / (1.f + expf(-zi));
        const float gf = 1.f / (1.f + expf(-zf));
        const float gg = tanhf(zg);
        const float go = 1.f / (1.f + expf(-zo));
        const float cn = gf * cst[mi * 4 + j] + gi * gg;
        cst[mi * 4 + j] = cn;
        const int rl = wm * 64 + mi * 16 + l4 * 4 + j;
        ht[rl * 40 + uloc] = f2h(go * tanhf(cn));
      }
    }
    __syncthreads();

    // ---- coalesced h writes (32 B/thread per dest) ----
    {
      const int rl = tid >> 1;
      const int seg = (tid & 1) * 16;
      const short8 v0 = *(const short8*)(ht + rl * 40 + seg);
      const short8 v1 = *(const short8*)(ht + rl * 40 + seg + 8);
      const long col = u0 + seg;
      if (d1) {
        short* p = d1 + (long)(m0 + rl) * s1 + o1 + col;
        *(short8*)p = v0; *(short8*)(p + 8) = v1;
      }
      if (d2) {
        short* p = d2 + (long)(m0 + rl) * 2048 + col;
        *(short8*)p = v0; *(short8*)(p + 8) = v1;
      }
      if (d3) {
        short* p = d3 + (long)(m0 + rl) * 1024 + col;
        *(short8*)p = v0; *(short8*)(p + 8) = v1;
      }
    }
    // ---- next-step embedding gather: 128-item slice per L0 block ----
    if (xq && tid < 128) {
      const int i = ut * 128 + tid;
      const int row = i >> 5;
      const int e8 = (i & 31) * 8;
      const int b = m0 + row;
      const int tok = tk[b];
      const short8 v = *(const short8*)(xe + (long)tok * 256 + e8);
      *(short8*)(xq + (long)b * xs + e8) = v;
    }

    // ---- publish: all stores drained (syncthreads), then release flag ----
    __syncthreads();
    if (tid == 0)
      __hip_atomic_store(fset(flags, role1, s, gy) + ut, 1u,
                         __ATOMIC_RELEASE, __HIP_MEMORY_SCOPE_AGENT);
  }
}

// fc projection: out[1:] = dh1_all @ fcWt^T + fc_b
__global__ __launch_bounds__(256) void fc_kernel(
    const short* __restrict__ A, const short* __restrict__ W,
    const float* __restrict__ bias, float* __restrict__ outp) {
  __shared__ short smem[32768];
  const int tid = threadIdx.x;
  const int lane = tid & 63;
  const int wv = tid >> 6;
  const int wm = wv >> 1;
  const int wu = wv & 1;
  const int l15 = lane & 15;
  const int l4 = lane >> 4;
  const int u0 = blockIdx.x * 128;
  const int m0 = blockIdx.y * 128;
  const int srow = lane >> 3;
  const int swseg = ((lane & 7) * 16) ^ (srow * 16);

  floatx4 acc[4][4];
#pragma unroll
  for (int g = 0; g < 4; ++g)
#pragma unroll
    for (int mi = 0; mi < 4; ++mi) acc[g][mi] = (floatx4){0.f, 0.f, 0.f, 0.f};

  const char* Ab = (const char*)A;
  const char* Wb = (const char*)W;
  const long kbytes = 2048;
  const int nkb = 16;

  auto stage = [&](int kb, int bufi) {
    const long kboff = (long)kb * 128;
    short* sb = smem + bufi * 16384;
#pragma unroll
    for (int ci = 0; ci < 8; ++ci) {
      const int c = wv * 8 + ci;
      void* lds = (void*)(sb + c * 512);
      if (c < 16) {
        const int row = c * 8 + srow;
        gload16(Ab + (long)(m0 + row) * kbytes + kboff + swseg, lds);
      } else {
        const int cb = c - 16;
        const int wrow = (cb >> 2) * 32 + u0 + (cb & 3) * 8 + srow;
        gload16(Wb + (long)wrow * kbytes + kboff + swseg, lds);
      }
    }
  };

  stage(0, 0);
  __syncthreads();
  int buf = 0;
  for (int kb = 0; kb < nkb; ++kb) {
    if (kb + 1 < nkb) stage(kb + 1, buf ^ 1);
    const short* sb = smem + buf * 16384;
#pragma unroll
    for (int k0 = 0; k0 < 64; k0 += 32) {
      short8 fa[4];
      short8 fb[4];
#pragma unroll
      for (int mi = 0; mi < 4; ++mi) {
        const int r = wm * 64 + mi * 16 + l15;
        fa[mi] = *(const short8*)(sb + r * 64 + ((k0 + l4 * 8) ^ ((r & 7) << 3)));
      }
      {
        const int r = wu * 16 + l15;
        const int kk = (k0 + l4 * 8) ^ ((r & 7) << 3);
#pragma unroll
        for (int g = 0; g < 4; ++g)
          fb[g] = *(const short8*)(sb + 8192 + (g * 32 + r) * 64 + kk);
      }
#pragma unroll
      for (int g = 0; g < 4; ++g)
#pragma unroll
        for (int mi = 0; mi < 4; ++mi)
          asm volatile("v_mfma_f32_16x16x32_f16 %0, %1, %2, %0"
                       : "+v"(acc[g][mi])
                       : "v"(fa[mi]), "v"(fb[g]));
    }
    __syncthreads();
    buf ^= 1;
  }
  asm volatile("s_nop 7\ns_nop 7\ns_nop 7");

#pragma unroll
  for (int g = 0; g < 4; ++g) {
    const int n = u0 + g * 32 + wu * 16 + l15;
    const float bb = bias[n];
#pragma unroll
    for (int mi = 0; mi < 4; ++mi) {
#pragma unroll
      for (int j = 0; j < 4; ++j) {
        const int r = m0 + wm * 64 + mi * 16 + l4 * 4 + j;
        outp[(long)r * 256 + n] = acc[g][mi][j] + bb;
      }
    }
  }
}

// weights -> fp16, [Wih | Whh] concat along K, gate-major rows, LINEAR layout
__global__ void wprep(const float* __restrict__ A, const float* __restrict__ B,
                      short* __restrict__ dst, int N, int Ka, int Kb) {
  const int ktot = Ka + Kb;
  const int n8 = ktot >> 3;
  const int total = N * n8;
  for (int idx = blockIdx.x * 256 + threadIdx.x; idx < total; idx += gridDim.x * 256) {
    const int n = idx / n8;
    const int k = (idx - n * n8) * 8;
    const float* s = (k < Ka) ? (A + (long)n * Ka + k) : (B + (long)n * Kb + (k - Ka));
    short8 v;
#pragma unroll
    for (int j = 0; j < 8; ++j) v[j] = f2h(s[j]);
    *(short8*)(dst + (long)n * ktot + k) = v;
  }
}

__global__ void embprep(const float* __restrict__ s, short* __restrict__ d, int total8) {
  const int idx = blockIdx.x * 256 + threadIdx.x;
  if (idx >= total8) return;
  short8 v;
#pragma unroll
  for (int j = 0; j < 8; ++j) v[j] = f2h(s[idx * 8 + j]);
  *(short8*)(d + idx * 8) = v;
}

// fc_W [1024][256] -> fcWt [256][1024] fp16, LINEAR
__global__ void fcwprep(const float* __restrict__ fcW, short* __restrict__ dst) {
  const int idx = blockIdx.x * 256 + threadIdx.x;  // 32768
  const int v = idx & 255;
  const int h = (idx >> 8) * 8;
  short8 o;
#pragma unroll
  for (int j = 0; j < 8; ++j) o[j] = f2h(fcW[(long)(h + j) * 256 + v]);
  *(short8*)(dst + (long)v * 1024 + h) = o;
}

// xe0 slot0: x = enc_emb[src[0]], h = 0 ; xe1 slot0 h-half = 0   (LINEAR)
__global__ void initk(const int* __restrict__ src, const float* __restrict__ emb,
                      short* __restrict__ xe0, short* __restrict__ xe1) {
  const int idx = blockIdx.x * 256 + threadIdx.x;
  if (idx < 1024 * 160) {
    const int b = idx / 160;
    const int k = (idx - b * 160) * 8;
    short8 v;
    if (k < 256) {
      const int tok = src[b];
#pragma unroll
      for (int j = 0; j < 8; ++j) v[j] = f2h(emb[(long)tok * 256 + k + j]);
    } else {
#pragma unroll
      for (int j = 0; j < 8; ++j) v[j] = 0;
    }
    *(short8*)(xe0 + (long)b * 1280 + k) = v;
  } else {
    const int i = idx - 1024 * 160;
    if (i < 1024 * 128) {
      const int b = i >> 7;
      const int k = 1024 + (i & 127) * 8;
      short8 v;
#pragma unroll
      for (int j = 0; j < 8; ++j) v[j] = 0;
      *(short8*)(xe1 + (long)b * 2048 + k) = v;
    }
  }
}

extern "C" void kernel_launch(void* const* d_in, const int* in_sizes, int n_in,
                              void* d_out, int out_size, void* d_ws, size_t ws_size,
                              hipStream_t stream) {
  (void)in_sizes; (void)n_in; (void)out_size; (void)ws_size;
  const int* src = (const int*)d_in[0];
  const int* tgt = (const int*)d_in[1];
  const float* enc_emb = (const float*)d_in[2];
  const float* eW0i = (const float*)d_in[3];
  const float* eW0h = (const float*)d_in[4];
  const float* eb0 = (const float*)d_in[5];
  const float* eW1i = (const float*)d_in[6];
  const float* eW1h = (const float*)d_in[7];
  const float* eb1 = (const float*)d_in[8];
  const float* dec_emb = (const float*)d_in[9];
  const float* dW0i = (const float*)d_in[10];
  const float* dW0h = (const float*)d_in[11];
  const float* db0 = (const float*)d_in[12];
  const float* dW1i = (const float*)d_in[13];
  const float* dW1h = (const float*)d_in[14];
  const float* db1 = (const float*)d_in[15];
  const float* fcW = (const float*)d_in[16];
  const float* fcb = (const float*)d_in[17];
  float* out = (float*)d_out;

  char* ws = (char*)d_ws;
  size_t off = 0;
  auto carve = [&](size_t bytes) {
    void* p = ws + off;
    off += (bytes + 255) & ~(size_t)255;
    return p;
  };
  short* wc_e0 = (short*)carve(4096l * 1280 * 2);
  short* wc_e1 = (short*)carve(4096l * 2048 * 2);
  short* wc_d0 = (short*)carve(4096l * 1280 * 2);
  short* wc_d1 = (short*)carve(4096l * 2048 * 2);
  short* fcwt = (short*)carve(256l * 1024 * 2);
  short* embe = (short*)carve(256l * 256 * 2);
  short* embd = (short*)carve(256l * 256 * 2);
  short* xe0 = (short*)carve(2l * 1024 * 1280 * 2);
  short* xe1 = (short*)carve(2l * 1024 * 2048 * 2);
  short* xd0 = (short*)carve(2l * 1024 * 1280 * 2);
  short* xd1 = (short*)carve(2l * 1024 * 2048 * 2);
  short* dh1 = (short*)carve(47l * 1024 * 1024 * 2);
  const size_t flagbytes = 2l * 79 * 8 * 32 * 4;
  unsigned* flags = (unsigned*)carve(flagbytes);

  hipMemsetAsync(flags, 0, flagbytes, stream);
  hipMemsetAsync(out, 0, 1024l * 256 * 4, stream);  // outputs[0] stays zeros

  wprep<<<2560, 256, 0, stream>>>(eW0i, eW0h, wc_e0, 4096, 256, 1024);
  wprep<<<4096, 256, 0, stream>>>(eW1i, eW1h, wc_e1, 4096, 1024, 1024);
  wprep<<<2560, 256, 0, stream>>>(dW0i, dW0h, wc_d0, 4096, 256, 1024);
  wprep<<<4096, 256, 0, stream>>>(dW1i, dW1h, wc_d1, 4096, 1024, 1024);
  embprep<<<32, 256, 0, stream>>>(enc_emb, embe, 8192);
  embprep<<<32, 256, 0, stream>>>(dec_emb, embd, 8192);
  fcwprep<<<128, 256, 0, stream>>>(fcW, fcwt);
  initk<<<1152, 256, 0, stream>>>(src, enc_emb, xe0, xe1);

  pers_kernel<<<dim3(64, 8), 256, 0, stream>>>(
      xe0, xe1, xd0, xd1, wc_e0, wc_e1, wc_d0, wc_d1,
      eb0, eb1, db0, db1, embe, embd, src, tgt, dh1, flags);

  fc_kernel<<<dim3(2, 376), 256, 0, stream>>>(dh1, fcwt, fcb, out + 1024l * 256);
}

// Round 9
// 4969.003 us; speedup vs baseline: 1.0132x; 1.0132x over previous
//
#include <hip/hip_runtime.h>
#include <hip/hip_fp16.h>

typedef __attribute__((ext_vector_type(8))) short short8;
typedef __attribute__((ext_vector_type(4))) float floatx4;

#define DEVFN static __device__ __forceinline__

DEVFN short f2h(float v) { return __half_as_short(__float2half(v)); }

DEVFN void gload16(const void* g, void* l) {
  void* gnc = const_cast<void*>(g);
  __builtin_amdgcn_global_load_lds(
      (__attribute__((address_space(1))) void*)gnc,
      (__attribute__((address_space(3))) void*)l, 16, 0, 0);
}

// flag set for (role, s, gy): 32 cells, one per u-tile block
DEVFN unsigned* fset(unsigned* f, int role, int s, int gy) {
  return f + ((((role * 79) + s) * 8 + gy) << 5);
}

// Persistent dataflow kernel: 79 sequential steps per role, point-to-point
// flag sync:  L1(s) <- {L0(s), L1(s-1)};  L0(s) <- {L0(s-1), L1(s-2)}.
// K-loop: K-step=32, 4 LDS buffers, prefetch depth 3, counted vmcnt
// (never 0 mid-loop) + raw s_barrier  [T3/T4].
// LDS swizzle (both-sides involution): 64 B rows, quad = 4*(r&1) ^ (l4 ^ ((r>>1)&3))
// -> exactly 8 lanes/quad (conflict-free baseline).
// Grid (64,8): bx<32 -> L0 (u-tile bx), bx>=32 -> L1 (u-tile bx-32).
__global__ __launch_bounds__(256, 2) void pers_kernel(
    short* xe0, short* xe1, short* xd0, short* xd1,
    const short* wc_e0, const short* wc_e1, const short* wc_d0, const short* wc_d1,
    const float* eb0, const float* eb1, const float* db0, const float* db1,
    const short* embe, const short* embd,
    const int* __restrict__ src, const int* __restrict__ tgt,
    short* dh1, unsigned* flags) {
  __shared__ short smem[32768];  // 4 buffers x (A 128x32 | W 128x32) fp16 = 64 KB
  const int tid = threadIdx.x;
  const int lane = tid & 63;
  const int wv = tid >> 6;   // 0..3
  const int wm = wv >> 1;    // 64-row group
  const int wu = wv & 1;     // 16-unit group
  const int l15 = lane & 15;
  const int l4 = lane >> 4;
  const int bx = blockIdx.x;
  const int role1 = bx >> 5;
  const int ut = bx & 31;
  const int u0 = ut * 32;
  const int gy = blockIdx.y;
  const int m0 = gy * 128;
  const int srow = lane >> 2;                                   // 0..15
  const int sswz = (((lane & 3) ^ ((srow >> 1) & 3)) << 4);     // src-side involution
  const long SL0 = 1024l * 1280, SL1 = 1024l * 2048;

  float cst[16];
#pragma unroll
  for (int i = 0; i < 16; ++i) cst[i] = 0.f;

  for (int s = 0; s < 79; ++s) {
    // ---- dependency wait (wave-0 lanes poll producer cells) ----
    unsigned* WA = nullptr;
    unsigned* WB = nullptr;
    if (!role1) {
      if (s >= 1) WA = fset(flags, 0, s - 1, gy);
      if (s >= 2) WB = fset(flags, 1, s - 2, gy);
    } else {
      WA = fset(flags, 0, s, gy);
      if (s >= 1) WB = fset(flags, 1, s - 1, gy);
    }
    if (WA || WB) {
      if (tid < 64) {
        unsigned* p = (tid < 32) ? (WA ? WA + tid : nullptr)
                                 : (WB ? WB + (tid - 32) : nullptr);
        if (p) {
          while (__hip_atomic_load(p, __ATOMIC_RELAXED,
                                   __HIP_MEMORY_SCOPE_AGENT) == 0u)
            __builtin_amdgcn_s_sleep(1);
          (void)__hip_atomic_load(p, __ATOMIC_ACQUIRE, __HIP_MEMORY_SCOPE_AGENT);
        }
      }
      __syncthreads();
    }

    // ---- step params ----
    const int enc = (s < 32) ? 1 : 0;
    const int t = enc ? s : s - 32;          // dec t = 0..46
    const int cur = t & 1, nxt = cur ^ 1;
    const short* A; const short* Wt; const float* bs; int ktot;
    short *d1 = nullptr, *d2 = nullptr, *d3 = nullptr, *xq = nullptr;
    int s1 = 0, o1 = 0, xs = 0;
    const short* xe = nullptr; const int* tk = nullptr;
    if (!role1) {
      if (enc) {
        A = xe0 + cur * SL0; Wt = wc_e0; bs = eb0; ktot = 1280;
        d2 = xe1 + cur * SL1;                 // hs0[t] -> enc L1 input (s=2048,o=0)
        s1 = 1280; o1 = 256; xs = 1280;
        if (t < 31) { d1 = xe0 + nxt * SL0; xq = d1; xe = embe; tk = src + (t + 1) * 1024; }
        else        { d1 = xd0;             xq = xd0; xe = embd; tk = tgt; }
      } else {
        A = xd0 + cur * SL0; Wt = wc_d0; bs = db0; ktot = 1280;
        d1 = xd0 + nxt * SL0; s1 = 1280; o1 = 256;
        d2 = xd1 + cur * SL1;                 // dh0 -> dec L1 input
        if (t < 46) { xq = xd0 + nxt * SL0; xs = 1280; xe = embd; tk = tgt + (t + 1) * 1024; }
      }
    } else {
      if (enc) {
        A = xe1 + cur * SL1; Wt = wc_e1; bs = eb1; ktot = 2048;
        d1 = (t < 31) ? (xe1 + nxt * SL1) : xd1; s1 = 2048; o1 = 1024;
      } else {
        A = xd1 + cur * SL1; Wt = wc_d1; bs = db1; ktot = 2048;
        d1 = xd1 + nxt * SL1; s1 = 2048; o1 = 1024;
        d3 = dh1 + (long)t * 1024 * 1024;     // archive dh1[t] (s=1024,o=0)
      }
    }

    // ---- GEMM: z = A @ W^T; deep-pipelined staging ----
    floatx4 acc[4][4];
#pragma unroll
    for (int g = 0; g < 4; ++g)
#pragma unroll
      for (int mi = 0; mi < 4; ++mi) acc[g][mi] = (floatx4){0.f, 0.f, 0.f, 0.f};

    const char* Ab = (const char*)A;
    const char* Wb = (const char*)Wt;
    const long kbytes = (long)ktot * 2;
    const int nkb = ktot >> 5;  // K=32 sub-tiles

    auto stage = [&](int kb, int bufi) {
      const long kboff = (long)kb * 64;
      short* sb = smem + bufi * 8192;
#pragma unroll
      for (int ci = 0; ci < 4; ++ci) {
        const int c = wv * 4 + ci;
        if (c < 8) {  // A: 16 rows per chunk
          const int row = m0 + c * 16 + srow;
          gload16(Ab + (long)row * kbytes + kboff + sswz, sb + c * 512);
        } else {      // W: 128 tile-rows = 4 gates x 32 units
          const int wr = (c - 8) * 16 + srow;
          const int wrow = (wr >> 5) * 1024 + u0 + (wr & 31);
          gload16(Wb + (long)wrow * kbytes + kboff + sswz, sb + 4096 + (c - 8) * 512);
        }
      }
    };

    // isolate vmcnt from prior-step stores / flag polls
    asm volatile("s_waitcnt vmcnt(0)" ::: "memory");
    stage(0, 0);
    stage(1, 1);
    stage(2, 2);
    for (int kb = 0; kb < nkb; ++kb) {
      if (kb + 2 < nkb)       asm volatile("s_waitcnt vmcnt(8)" ::: "memory");
      else if (kb + 1 < nkb)  asm volatile("s_waitcnt vmcnt(4)" ::: "memory");
      else                    asm volatile("s_waitcnt vmcnt(0)" ::: "memory");
      __builtin_amdgcn_sched_barrier(0);
      __builtin_amdgcn_s_barrier();        // all waves: buf[kb] ready
      __builtin_amdgcn_sched_barrier(0);
      if (kb + 3 < nkb) stage(kb + 3, (kb + 3) & 3);  // WAR-safe (reads of that buf
                                                      // completed before this barrier)
      __builtin_amdgcn_sched_barrier(0);
      const short* sb = smem + (kb & 3) * 8192;
      short8 fa[4];
      short8 fb[4];
#pragma unroll
      for (int mi = 0; mi < 4; ++mi) {
        const int r = wm * 64 + mi * 16 + l15;
        fa[mi] = *(const short8*)(sb + r * 32 + ((l4 * 8) ^ (((r >> 1) & 3) << 3)));
      }
#pragma unroll
      for (int g = 0; g < 4; ++g) {
        const int r = g * 32 + wu * 16 + l15;
        fb[g] = *(const short8*)(sb + 4096 + r * 32 + ((l4 * 8) ^ (((r >> 1) & 3) << 3)));
      }
#pragma unroll
      for (int g = 0; g < 4; ++g)
#pragma unroll
        for (int mi = 0; mi < 4; ++mi)
          asm volatile("v_mfma_f32_16x16x32_f16 %0, %1, %2, %0"
                       : "+v"(acc[g][mi])
                       : "v"(fa[mi]), "v"(fb[g]));
    }
    __syncthreads();  // all LDS reads retired before ht overwrites buf0
    asm volatile("s_nop 7\ns_nop 7\ns_nop 7");  // MFMA -> VALU hazard guard

    // ---- LSTM cell (c in regs) -> h into LDS transpose tile ----
    const int u = u0 + wu * 16 + l15;
    const float bi = bs[u];
    const float bf_ = bs[1024 + u];
    const float bg = bs[2048 + u];
    const float bo = bs[3072 + u];
    short* ht = smem;  // [128][40] fp16, overlays buf0/buf1
    const int uloc = wu * 16 + l15;
#pragma unroll
    for (int mi = 0; mi < 4; ++mi) {
#pragma unroll
      for (int j = 0; j < 4; ++j) {
        const float zi = acc[0][mi][j] + bi;
        const float zf = acc[1][mi][j] + bf_;
        const float zg = acc[2][mi][j] + bg;
        const float zo = acc[3][mi][j] + bo;
        const float gi = 1.f / (1.f + expf(-zi));
        const float gf = 1.f / (1.f + expf(-zf));
        const float gg = tanhf(zg);
        const float go = 1.f / (1.f + expf(-zo));
        const float cn = gf * cst[mi * 4 + j] + gi * gg;
        cst[mi * 4 + j] = cn;
        const int rl = wm * 64 + mi * 16 + l4 * 4 + j;
        ht[rl * 40 + uloc] = f2h(go * tanhf(cn));
      }
    }
    __syncthreads();

    // ---- coalesced h writes (32 B/thread per dest) ----
    {
      const int rl = tid >> 1;
      const int seg = (tid & 1) * 16;
      const short8 v0 = *(const short8*)(ht + rl * 40 + seg);
      const short8 v1 = *(const short8*)(ht + rl * 40 + seg + 8);
      const long col = u0 + seg;
      if (d1) {
        short* p = d1 + (long)(m0 + rl) * s1 + o1 + col;
        *(short8*)p = v0; *(short8*)(p + 8) = v1;
      }
      if (d2) {
        short* p = d2 + (long)(m0 + rl) * 2048 + col;
        *(short8*)p = v0; *(short8*)(p + 8) = v1;
      }
      if (d3) {
        short* p = d3 + (long)(m0 + rl) * 1024 + col;
        *(short8*)p = v0; *(short8*)(p + 8) = v1;
      }
    }
    // ---- next-step embedding gather: 128-item slice per L0 block ----
    if (xq && tid < 128) {
      const int i = ut * 128 + tid;
      const int row = i >> 5;
      const int e8 = (i & 31) * 8;
      const int b = m0 + row;
      const int tok = tk[b];
      const short8 v = *(const short8*)(xe + (long)tok * 256 + e8);
      *(short8*)(xq + (long)b * xs + e8) = v;
    }

    // ---- publish: all stores drained (syncthreads), then release flag ----
    __syncthreads();
    if (tid == 0)
      __hip_atomic_store(fset(flags, role1, s, gy) + ut, 1u,
                         __ATOMIC_RELEASE, __HIP_MEMORY_SCOPE_AGENT);
  }
}

// fc projection: out[1:] = dh1_all @ fcWt^T + fc_b
__global__ __launch_bounds__(256) void fc_kernel(
    const short* __restrict__ A, const short* __restrict__ W,
    const float* __restrict__ bias, float* __restrict__ outp) {
  __shared__ short smem[32768];
  const int tid = threadIdx.x;
  const int lane = tid & 63;
  const int wv = tid >> 6;
  const int wm = wv >> 1;
  const int wu = wv & 1;
  const int l15 = lane & 15;
  const int l4 = lane >> 4;
  const int u0 = blockIdx.x * 128;
  const int m0 = blockIdx.y * 128;
  const int srow = lane >> 3;
  const int swseg = ((lane & 7) * 16) ^ (srow * 16);

  floatx4 acc[4][4];
#pragma unroll
  for (int g = 0; g < 4; ++g)
#pragma unroll
    for (int mi = 0; mi < 4; ++mi) acc[g][mi] = (floatx4){0.f, 0.f, 0.f, 0.f};

  const char* Ab = (const char*)A;
  const char* Wb = (const char*)W;
  const long kbytes = 2048;
  const int nkb = 16;

  auto stage = [&](int kb, int bufi) {
    const long kboff = (long)kb * 128;
    short* sb = smem + bufi * 16384;
#pragma unroll
    for (int ci = 0; ci < 8; ++ci) {
      const int c = wv * 8 + ci;
      void* lds = (void*)(sb + c * 512);
      if (c < 16) {
        const int row = c * 8 + srow;
        gload16(Ab + (long)(m0 + row) * kbytes + kboff + swseg, lds);
      } else {
        const int cb = c - 16;
        const int wrow = (cb >> 2) * 32 + u0 + (cb & 3) * 8 + srow;
        gload16(Wb + (long)wrow * kbytes + kboff + swseg, lds);
      }
    }
  };

  stage(0, 0);
  __syncthreads();
  int buf = 0;
  for (int kb = 0; kb < nkb; ++kb) {
    if (kb + 1 < nkb) stage(kb + 1, buf ^ 1);
    const short* sb = smem + buf * 16384;
#pragma unroll
    for (int k0 = 0; k0 < 64; k0 += 32) {
      short8 fa[4];
      short8 fb[4];
#pragma unroll
      for (int mi = 0; mi < 4; ++mi) {
        const int r = wm * 64 + mi * 16 + l15;
        fa[mi] = *(const short8*)(sb + r * 64 + ((k0 + l4 * 8) ^ ((r & 7) << 3)));
      }
      {
        const int r = wu * 16 + l15;
        const int kk = (k0 + l4 * 8) ^ ((r & 7) << 3);
#pragma unroll
        for (int g = 0; g < 4; ++g)
          fb[g] = *(const short8*)(sb + 8192 + (g * 32 + r) * 64 + kk);
      }
#pragma unroll
      for (int g = 0; g < 4; ++g)
#pragma unroll
        for (int mi = 0; mi < 4; ++mi)
          asm volatile("v_mfma_f32_16x16x32_f16 %0, %1, %2, %0"
                       : "+v"(acc[g][mi])
                       : "v"(fa[mi]), "v"(fb[g]));
    }
    __syncthreads();
    buf ^= 1;
  }
  asm volatile("s_nop 7\ns_nop 7\ns_nop 7");

#pragma unroll
  for (int g = 0; g < 4; ++g) {
    const int n = u0 + g * 32 + wu * 16 + l15;
    const float bb = bias[n];
#pragma unroll
    for (int mi = 0; mi < 4; ++mi) {
#pragma unroll
      for (int j = 0; j < 4; ++j) {
        const int r = m0 + wm * 64 + mi * 16 + l4 * 4 + j;
        outp[(long)r * 256 + n] = acc[g][mi][j] + bb;
      }
    }
  }
}

// weights -> fp16, [Wih | Whh] concat along K, gate-major rows, LINEAR layout
__global__ void wprep(const float* __restrict__ A, const float* __restrict__ B,
                      short* __restrict__ dst, int N, int Ka, int Kb) {
  const int ktot = Ka + Kb;
  const int n8 = ktot >> 3;
  const int total = N * n8;
  for (int idx = blockIdx.x * 256 + threadIdx.x; idx < total; idx += gridDim.x * 256) {
    const int n = idx / n8;
    const int k = (idx - n * n8) * 8;
    const float* s = (k < Ka) ? (A + (long)n * Ka + k) : (B + (long)n * Kb + (k - Ka));
    short8 v;
#pragma unroll
    for (int j = 0; j < 8; ++j) v[j] = f2h(s[j]);
    *(short8*)(dst + (long)n * ktot + k) = v;
  }
}

__global__ void embprep(const float* __restrict__ s, short* __restrict__ d, int total8) {
  const int idx = blockIdx.x * 256 + threadIdx.x;
  if (idx >= total8) return;
  short8 v;
#pragma unroll
  for (int j = 0; j < 8; ++j) v[j] = f2h(s[idx * 8 + j]);
  *(short8*)(d + idx * 8) = v;
}

// fc_W [1024][256] -> fcWt [256][1024] fp16, LINEAR
__global__ void fcwprep(const float* __restrict__ fcW, short* __restrict__ dst) {
  const int idx = blockIdx.x * 256 + threadIdx.x;  // 32768
  const int v = idx & 255;
  const int h = (idx >> 8) * 8;
  short8 o;
#pragma unroll
  for (int j = 0; j < 8; ++j) o[j] = f2h(fcW[(long)(h + j) * 256 + v]);
  *(short8*)(dst + (long)v * 1024 + h) = o;
}

// xe0 slot0: x = enc_emb[src[0]], h = 0 ; xe1 slot0 h-half = 0   (LINEAR)
__global__ void initk(const int* __restrict__ src, const float* __restrict__ emb,
                      short* __restrict__ xe0, short* __restrict__ xe1) {
  const int idx = blockIdx.x * 256 + threadIdx.x;
  if (idx < 1024 * 160) {
    const int b = idx / 160;
    const int k = (idx - b * 160) * 8;
    short8 v;
    if (k < 256) {
      const int tok = src[b];
#pragma unroll
      for (int j = 0; j < 8; ++j) v[j] = f2h(emb[(long)tok * 256 + k + j]);
    } else {
#pragma unroll
      for (int j = 0; j < 8; ++j) v[j] = 0;
    }
    *(short8*)(xe0 + (long)b * 1280 + k) = v;
  } else {
    const int i = idx - 1024 * 160;
    if (i < 1024 * 128) {
      const int b = i >> 7;
      const int k = 1024 + (i & 127) * 8;
      short8 v;
#pragma unroll
      for (int j = 0; j < 8; ++j) v[j] = 0;
      *(short8*)(xe1 + (long)b * 2048 + k) = v;
    }
  }
}

extern "C" void kernel_launch(void* const* d_in, const int* in_sizes, int n_in,
                              void* d_out, int out_size, void* d_ws, size_t ws_size,
                              hipStream_t stream) {
  (void)in_sizes; (void)n_in; (void)out_size; (void)ws_size;
  const int* src = (const int*)d_in[0];
  const int* tgt = (const int*)d_in[1];
  const float* enc_emb = (const float*)d_in[2];
  const float* eW0i = (const float*)d_in[3];
  const float* eW0h = (const float*)d_in[4];
  const float* eb0 = (const float*)d_in[5];
  const float* eW1i = (const float*)d_in[6];
  const float* eW1h = (const float*)d_in[7];
  const float* eb1 = (const float*)d_in[8];
  const float* dec_emb = (const float*)d_in[9];
  const float* dW0i = (const float*)d_in[10];
  const float* dW0h = (const float*)d_in[11];
  const float* db0 = (const float*)d_in[12];
  const float* dW1i = (const float*)d_in[13];
  const float* dW1h = (const float*)d_in[14];
  const float* db1 = (const float*)d_in[15];
  const float* fcW = (const float*)d_in[16];
  const float* fcb = (const float*)d_in[17];
  float* out = (float*)d_out;

  char* ws = (char*)d_ws;
  size_t off = 0;
  auto carve = [&](size_t bytes) {
    void* p = ws + off;
    off += (bytes + 255) & ~(size_t)255;
    return p;
  };
  short* wc_e0 = (short*)carve(4096l * 1280 * 2);
  short* wc_e1 = (short*)carve(4096l * 2048 * 2);
  short* wc_d0 = (short*)carve(4096l * 1280 * 2);
  short* wc_d1 = (short*)carve(4096l * 2048 * 2);
  short* fcwt = (short*)carve(256l * 1024 * 2);
  short* embe = (short*)carve(256l * 256 * 2);
  short* embd = (short*)carve(256l * 256 * 2);
  short* xe0 = (short*)carve(2l * 1024 * 1280 * 2);
  short* xe1 = (short*)carve(2l * 1024 * 2048 * 2);
  short* xd0 = (short*)carve(2l * 1024 * 1280 * 2);
  short* xd1 = (short*)carve(2l * 1024 * 2048 * 2);
  short* dh1 = (short*)carve(47l * 1024 * 1024 * 2);
  const size_t flagbytes = 2l * 79 * 8 * 32 * 4;
  unsigned* flags = (unsigned*)carve(flagbytes);

  hipMemsetAsync(flags, 0, flagbytes, stream);
  hipMemsetAsync(out, 0, 1024l * 256 * 4, stream);  // outputs[0] stays zeros

  wprep<<<2560, 256, 0, stream>>>(eW0i, eW0h, wc_e0, 4096, 256, 1024);
  wprep<<<4096, 256, 0, stream>>>(eW1i, eW1h, wc_e1, 4096, 1024, 1024);
  wprep<<<2560, 256, 0, stream>>>(dW0i, dW0h, wc_d0, 4096, 256, 1024);
  wprep<<<4096, 256, 0, stream>>>(dW1i, dW1h, wc_d1, 4096, 1024, 1024);
  embprep<<<32, 256, 0, stream>>>(enc_emb, embe, 8192);
  embprep<<<32, 256, 0, stream>>>(dec_emb, embd, 8192);
  fcwprep<<<128, 256, 0, stream>>>(fcW, fcwt);
  initk<<<1152, 256, 0, stream>>>(src, enc_emb, xe0, xe1);

  pers_kernel<<<dim3(64, 8), 256, 0, stream>>>(
      xe0, xe1, xd0, xd1, wc_e0, wc_e1, wc_d0, wc_d1,
      eb0, eb1, db0, db1, embe, embd, src, tgt, dh1, flags);

  fc_kernel<<<dim3(2, 376), 256, 0, stream>>>(dh1, fcwt, fcb, out + 1024l * 256);
}

// Round 10
// 4217.090 us; speedup vs baseline: 1.1938x; 1.1783x over previous
//
#include <hip/hip_runtime.h>
#include <hip/hip_fp16.h>

typedef __attribute__((ext_vector_type(8))) short short8;
typedef __attribute__((ext_vector_type(4))) float floatx4;

#define DEVFN static __device__ __forceinline__

DEVFN short f2h(float v) { return __half_as_short(__float2half(v)); }

DEVFN void gload16(const void* g, void* l) {
  void* gnc = const_cast<void*>(g);
  __builtin_amdgcn_global_load_lds(
      (__attribute__((address_space(1))) void*)gnc,
      (__attribute__((address_space(3))) void*)l, 16, 0, 0);
}

// flag set for (role, s, gy): 32 cells, one per u-tile block
DEVFN unsigned* fset(unsigned* f, int role, int s, int gy) {
  return f + ((((role * 79) + s) * 8 + gy) << 5);
}

// Persistent dataflow kernel: 79 sequential steps per role, point-to-point
// flag sync:  L1(s) <- {L0(s), L1(s-1)};  L0(s) <- {L0(s-1), L1(s-2)}.
// K-loop: R7-proven (K=64, 2 LDS buffers, syncthreads).
// NEW (T1): XCD-aware placement — flat grid 512, XCD = bid%8 owns unit
// superblock [128*xcd, 128*xcd+128) for BOTH layers -> per-XCD W working set
// = 3.4 MB < 4 MB L2 -> W becomes L2-resident instead of re-streaming.
__global__ __launch_bounds__(256, 2) void pers_kernel(
    short* xe0, short* xe1, short* xd0, short* xd1,
    const short* wc_e0, const short* wc_e1, const short* wc_d0, const short* wc_d1,
    const float* eb0, const float* eb1, const float* db0, const float* db1,
    const short* embe, const short* embd,
    const int* __restrict__ src, const int* __restrict__ tgt,
    short* dh1, unsigned* flags) {
  __shared__ short smem[32768];  // 2 buffers x (A 128x64 | W 128x64) fp16 = 64 KB
  const int tid = threadIdx.x;
  const int lane = tid & 63;
  const int wv = tid >> 6;   // 0..3
  const int wm = wv >> 1;    // 64-row group
  const int wu = wv & 1;     // 16-unit group
  const int l15 = lane & 15;
  const int l4 = lane >> 4;
  // ---- XCD-aware decode: xcd = bid%8 (HW round-robin), owns 4 u-tiles ----
  const int bid = blockIdx.x;          // 0..511
  const int xcd = bid & 7;
  const int idx = bid >> 3;            // 0..63 within XCD
  const int role1 = idx >> 5;          // 0 = L0, 1 = L1
  const int rem = idx & 31;
  const int ut = xcd * 4 + (rem >> 3); // 0..31 unit tile (32 units)
  const int gy = rem & 7;              // batch group
  const int u0 = ut * 32;
  const int m0 = gy * 128;
  const int srow = lane >> 3;
  const int swseg = ((lane & 7) * 16) ^ (srow * 16);  // source-side LDS swizzle
  const long SL0 = 1024l * 1280, SL1 = 1024l * 2048;

  float cst[16];
#pragma unroll
  for (int i = 0; i < 16; ++i) cst[i] = 0.f;

  for (int s = 0; s < 79; ++s) {
    // ---- dependency wait (wave-0 lanes poll producer cells) ----
    unsigned* WA = nullptr;
    unsigned* WB = nullptr;
    if (!role1) {
      if (s >= 1) WA = fset(flags, 0, s - 1, gy);
      if (s >= 2) WB = fset(flags, 1, s - 2, gy);
    } else {
      WA = fset(flags, 0, s, gy);
      if (s >= 1) WB = fset(flags, 1, s - 1, gy);
    }
    if (WA || WB) {
      if (tid < 64) {
        unsigned* p = (tid < 32) ? (WA ? WA + tid : nullptr)
                                 : (WB ? WB + (tid - 32) : nullptr);
        if (p) {
          while (__hip_atomic_load(p, __ATOMIC_RELAXED,
                                   __HIP_MEMORY_SCOPE_AGENT) == 0u)
            __builtin_amdgcn_s_sleep(1);
          (void)__hip_atomic_load(p, __ATOMIC_ACQUIRE, __HIP_MEMORY_SCOPE_AGENT);
        }
      }
      __syncthreads();
    }

    // ---- step params ----
    const int enc = (s < 32) ? 1 : 0;
    const int t = enc ? s : s - 32;          // dec t = 0..46
    const int cur = t & 1, nxt = cur ^ 1;
    const short* A; const short* Wt; const float* bs; int ktot;
    short *d1 = nullptr, *d2 = nullptr, *d3 = nullptr, *xq = nullptr;
    int s1 = 0, o1 = 0, xs = 0;
    const short* xe = nullptr; const int* tk = nullptr;
    if (!role1) {
      if (enc) {
        A = xe0 + cur * SL0; Wt = wc_e0; bs = eb0; ktot = 1280;
        d2 = xe1 + cur * SL1;                 // hs0[t] -> enc L1 input (s=2048,o=0)
        s1 = 1280; o1 = 256; xs = 1280;
        if (t < 31) { d1 = xe0 + nxt * SL0; xq = d1; xe = embe; tk = src + (t + 1) * 1024; }
        else        { d1 = xd0;             xq = xd0; xe = embd; tk = tgt; }
      } else {
        A = xd0 + cur * SL0; Wt = wc_d0; bs = db0; ktot = 1280;
        d1 = xd0 + nxt * SL0; s1 = 1280; o1 = 256;
        d2 = xd1 + cur * SL1;                 // dh0 -> dec L1 input
        if (t < 46) { xq = xd0 + nxt * SL0; xs = 1280; xe = embd; tk = tgt + (t + 1) * 1024; }
      }
    } else {
      if (enc) {
        A = xe1 + cur * SL1; Wt = wc_e1; bs = eb1; ktot = 2048;
        d1 = (t < 31) ? (xe1 + nxt * SL1) : xd1; s1 = 2048; o1 = 1024;
      } else {
        A = xd1 + cur * SL1; Wt = wc_d1; bs = db1; ktot = 2048;
        d1 = xd1 + nxt * SL1; s1 = 2048; o1 = 1024;
        d3 = dh1 + (long)t * 1024 * 1024;     // archive dh1[t] (s=1024,o=0)
      }
    }

    // ---- GEMM: z = A @ W^T, 2-buffer LDS pipeline (R7-proven) ----
    floatx4 acc[4][4];
#pragma unroll
    for (int g = 0; g < 4; ++g)
#pragma unroll
      for (int mi = 0; mi < 4; ++mi) acc[g][mi] = (floatx4){0.f, 0.f, 0.f, 0.f};

    const char* Ab = (const char*)A;
    const char* Wb = (const char*)Wt;
    const long kbytes = (long)ktot * 2;
    const int nkb = ktot >> 6;

    auto stage = [&](int kb, int bufi) {
      const long kboff = (long)kb * 128;
      short* sb = smem + bufi * 16384;
#pragma unroll
      for (int ci = 0; ci < 8; ++ci) {
        const int c = wv * 8 + ci;
        void* lds = (void*)(sb + c * 512);
        if (c < 16) {  // A chunks
          const int row = c * 8 + srow;
          gload16(Ab + (long)(m0 + row) * kbytes + kboff + swseg, lds);
        } else {       // W chunks: 4 gates x 32 units
          const int cb = c - 16;
          const int wrow = (cb >> 2) * 1024 + u0 + (cb & 3) * 8 + srow;
          gload16(Wb + (long)wrow * kbytes + kboff + swseg, lds);
        }
      }
    };

    stage(0, 0);
    __syncthreads();
    int buf = 0;
    for (int kb = 0; kb < nkb; ++kb) {
      if (kb + 1 < nkb) stage(kb + 1, buf ^ 1);  // prefetch under compute
      const short* sb = smem + buf * 16384;
#pragma unroll
      for (int k0 = 0; k0 < 64; k0 += 32) {
        short8 fa[4];
        short8 fb[4];
#pragma unroll
        for (int mi = 0; mi < 4; ++mi) {
          const int r = wm * 64 + mi * 16 + l15;
          fa[mi] = *(const short8*)(sb + r * 64 + ((k0 + l4 * 8) ^ ((r & 7) << 3)));
        }
        {
          const int r = wu * 16 + l15;
          const int kk = (k0 + l4 * 8) ^ ((r & 7) << 3);
#pragma unroll
          for (int g = 0; g < 4; ++g)
            fb[g] = *(const short8*)(sb + 8192 + (g * 32 + r) * 64 + kk);
        }
#pragma unroll
        for (int g = 0; g < 4; ++g)
#pragma unroll
          for (int mi = 0; mi < 4; ++mi)
            asm volatile("v_mfma_f32_16x16x32_f16 %0, %1, %2, %0"
                         : "+v"(acc[g][mi])
                         : "v"(fa[mi]), "v"(fb[g]));
      }
      __syncthreads();
      buf ^= 1;
    }
    asm volatile("s_nop 7\ns_nop 7\ns_nop 7");  // MFMA -> VALU hazard guard

    // ---- LSTM cell (c in regs) -> h into LDS transpose tile ----
    const int u = u0 + wu * 16 + l15;
    const float bi = bs[u];
    const float bf_ = bs[1024 + u];
    const float bg = bs[2048 + u];
    const float bo = bs[3072 + u];
    short* ht = smem;  // [128][40] fp16, reuses buf0 (all LDS reads done)
    const int uloc = wu * 16 + l15;
#pragma unroll
    for (int mi = 0; mi < 4; ++mi) {
#pragma unroll
      for (int j = 0; j < 4; ++j) {
        const float zi = acc[0][mi][j] + bi;
        const float zf = acc[1][mi][j] + bf_;
        const float zg = acc[2][mi][j] + bg;
        const float zo = acc[3][mi][j] + bo;
        const float gi = 1.f / (1.f + expf(-zi));
        const float gf = 1.f / (1.f + expf(-zf));
        const float gg = tanhf(zg);
        const float go = 1.f / (1.f + expf(-zo));
        const float cn = gf * cst[mi * 4 + j] + gi * gg;
        cst[mi * 4 + j] = cn;
        const int rl = wm * 64 + mi * 16 + l4 * 4 + j;
        ht[rl * 40 + uloc] = f2h(go * tanhf(cn));
      }
    }
    __syncthreads();

    // ---- coalesced h writes (32 B/thread per dest) ----
    {
      const int rl = tid >> 1;
      const int seg = (tid & 1) * 16;
      const short8 v0 = *(const short8*)(ht + rl * 40 + seg);
      const short8 v1 = *(const short8*)(ht + rl * 40 + seg + 8);
      const long col = u0 + seg;
      if (d1) {
        short* p = d1 + (long)(m0 + rl) * s1 + o1 + col;
        *(short8*)p = v0; *(short8*)(p + 8) = v1;
      }
      if (d2) {
        short* p = d2 + (long)(m0 + rl) * 2048 + col;
        *(short8*)p = v0; *(short8*)(p + 8) = v1;
      }
      if (d3) {
        short* p = d3 + (long)(m0 + rl) * 1024 + col;
        *(short8*)p = v0; *(short8*)(p + 8) = v1;
      }
    }
    // ---- next-step embedding gather: 128-item slice per L0 block ----
    if (xq && tid < 128) {
      const int i = ut * 128 + tid;
      const int row = i >> 5;
      const int e8 = (i & 31) * 8;
      const int b = m0 + row;
      const int tok = tk[b];
      const short8 v = *(const short8*)(xe + (long)tok * 256 + e8);
      *(short8*)(xq + (long)b * xs + e8) = v;
    }

    // ---- publish: all stores drained (syncthreads), then release flag ----
    __syncthreads();
    if (tid == 0)
      __hip_atomic_store(fset(flags, role1, s, gy) + ut, 1u,
                         __ATOMIC_RELEASE, __HIP_MEMORY_SCOPE_AGENT);
  }
}

// fc projection: out[1:] = dh1_all @ fcWt^T + fc_b
__global__ __launch_bounds__(256) void fc_kernel(
    const short* __restrict__ A, const short* __restrict__ W,
    const float* __restrict__ bias, float* __restrict__ outp) {
  __shared__ short smem[32768];
  const int tid = threadIdx.x;
  const int lane = tid & 63;
  const int wv = tid >> 6;
  const int wm = wv >> 1;
  const int wu = wv & 1;
  const int l15 = lane & 15;
  const int l4 = lane >> 4;
  const int u0 = blockIdx.x * 128;
  const int m0 = blockIdx.y * 128;
  const int srow = lane >> 3;
  const int swseg = ((lane & 7) * 16) ^ (srow * 16);

  floatx4 acc[4][4];
#pragma unroll
  for (int g = 0; g < 4; ++g)
#pragma unroll
    for (int mi = 0; mi < 4; ++mi) acc[g][mi] = (floatx4){0.f, 0.f, 0.f, 0.f};

  const char* Ab = (const char*)A;
  const char* Wb = (const char*)W;
  const long kbytes = 2048;
  const int nkb = 16;

  auto stage = [&](int kb, int bufi) {
    const long kboff = (long)kb * 128;
    short* sb = smem + bufi * 16384;
#pragma unroll
    for (int ci = 0; ci < 8; ++ci) {
      const int c = wv * 8 + ci;
      void* lds = (void*)(sb + c * 512);
      if (c < 16) {
        const int row = c * 8 + srow;
        gload16(Ab + (long)(m0 + row) * kbytes + kboff + swseg, lds);
      } else {
        const int cb = c - 16;
        const int wrow = (cb >> 2) * 32 + u0 + (cb & 3) * 8 + srow;
        gload16(Wb + (long)wrow * kbytes + kboff + swseg, lds);
      }
    }
  };

  stage(0, 0);
  __syncthreads();
  int buf = 0;
  for (int kb = 0; kb < nkb; ++kb) {
    if (kb + 1 < nkb) stage(kb + 1, buf ^ 1);
    const short* sb = smem + buf * 16384;
#pragma unroll
    for (int k0 = 0; k0 < 64; k0 += 32) {
      short8 fa[4];
      short8 fb[4];
#pragma unroll
      for (int mi = 0; mi < 4; ++mi) {
        const int r = wm * 64 + mi * 16 + l15;
        fa[mi] = *(const short8*)(sb + r * 64 + ((k0 + l4 * 8) ^ ((r & 7) << 3)));
      }
      {
        const int r = wu * 16 + l15;
        const int kk = (k0 + l4 * 8) ^ ((r & 7) << 3);
#pragma unroll
        for (int g = 0; g < 4; ++g)
          fb[g] = *(const short8*)(sb + 8192 + (g * 32 + r) * 64 + kk);
      }
#pragma unroll
      for (int g = 0; g < 4; ++g)
#pragma unroll
        for (int mi = 0; mi < 4; ++mi)
          asm volatile("v_mfma_f32_16x16x32_f16 %0, %1, %2, %0"
                       : "+v"(acc[g][mi])
                       : "v"(fa[mi]), "v"(fb[g]));
    }
    __syncthreads();
    buf ^= 1;
  }
  asm volatile("s_nop 7\ns_nop 7\ns_nop 7");

#pragma unroll
  for (int g = 0; g < 4; ++g) {
    const int n = u0 + g * 32 + wu * 16 + l15;
    const float bb = bias[n];
#pragma unroll
    for (int mi = 0; mi < 4; ++mi) {
#pragma unroll
      for (int j = 0; j < 4; ++j) {
        const int r = m0 + wm * 64 + mi * 16 + l4 * 4 + j;
        outp[(long)r * 256 + n] = acc[g][mi][j] + bb;
      }
    }
  }
}

// weights -> fp16, [Wih | Whh] concat along K, gate-major rows, LINEAR layout
__global__ void wprep(const float* __restrict__ A, const float* __restrict__ B,
                      short* __restrict__ dst, int N, int Ka, int Kb) {
  const int ktot = Ka + Kb;
  const int n8 = ktot >> 3;
  const int total = N * n8;
  for (int idx = blockIdx.x * 256 + threadIdx.x; idx < total; idx += gridDim.x * 256) {
    const int n = idx / n8;
    const int k = (idx - n * n8) * 8;
    const float* s = (k < Ka) ? (A + (long)n * Ka + k) : (B + (long)n * Kb + (k - Ka));
    short8 v;
#pragma unroll
    for (int j = 0; j < 8; ++j) v[j] = f2h(s[j]);
    *(short8*)(dst + (long)n * ktot + k) = v;
  }
}

__global__ void embprep(const float* __restrict__ s, short* __restrict__ d, int total8) {
  const int idx = blockIdx.x * 256 + threadIdx.x;
  if (idx >= total8) return;
  short8 v;
#pragma unroll
  for (int j = 0; j < 8; ++j) v[j] = f2h(s[idx * 8 + j]);
  *(short8*)(d + idx * 8) = v;
}

// fc_W [1024][256] -> fcWt [256][1024] fp16, LINEAR
__global__ void fcwprep(const float* __restrict__ fcW, short* __restrict__ dst) {
  const int idx = blockIdx.x * 256 + threadIdx.x;  // 32768
  const int v = idx & 255;
  const int h = (idx >> 8) * 8;
  short8 o;
#pragma unroll
  for (int j = 0; j < 8; ++j) o[j] = f2h(fcW[(long)(h + j) * 256 + v]);
  *(short8*)(dst + (long)v * 1024 + h) = o;
}

// xe0 slot0: x = enc_emb[src[0]], h = 0 ; xe1 slot0 h-half = 0   (LINEAR)
__global__ void initk(const int* __restrict__ src, const float* __restrict__ emb,
                      short* __restrict__ xe0, short* __restrict__ xe1) {
  const int idx = blockIdx.x * 256 + threadIdx.x;
  if (idx < 1024 * 160) {
    const int b = idx / 160;
    const int k = (idx - b * 160) * 8;
    short8 v;
    if (k < 256) {
      const int tok = src[b];
#pragma unroll
      for (int j = 0; j < 8; ++j) v[j] = f2h(emb[(long)tok * 256 + k + j]);
    } else {
#pragma unroll
      for (int j = 0; j < 8; ++j) v[j] = 0;
    }
    *(short8*)(xe0 + (long)b * 1280 + k) = v;
  } else {
    const int i = idx - 1024 * 160;
    if (i < 1024 * 128) {
      const int b = i >> 7;
      const int k = 1024 + (i & 127) * 8;
      short8 v;
#pragma unroll
      for (int j = 0; j < 8; ++j) v[j] = 0;
      *(short8*)(xe1 + (long)b * 2048 + k) = v;
    }
  }
}

extern "C" void kernel_launch(void* const* d_in, const int* in_sizes, int n_in,
                              void* d_out, int out_size, void* d_ws, size_t ws_size,
                              hipStream_t stream) {
  (void)in_sizes; (void)n_in; (void)out_size; (void)ws_size;
  const int* src = (const int*)d_in[0];
  const int* tgt = (const int*)d_in[1];
  const float* enc_emb = (const float*)d_in[2];
  const float* eW0i = (const float*)d_in[3];
  const float* eW0h = (const float*)d_in[4];
  const float* eb0 = (const float*)d_in[5];
  const float* eW1i = (const float*)d_in[6];
  const float* eW1h = (const float*)d_in[7];
  const float* eb1 = (const float*)d_in[8];
  const float* dec_emb = (const float*)d_in[9];
  const float* dW0i = (const float*)d_in[10];
  const float* dW0h = (const float*)d_in[11];
  const float* db0 = (const float*)d_in[12];
  const float* dW1i = (const float*)d_in[13];
  const float* dW1h = (const float*)d_in[14];
  const float* db1 = (const float*)d_in[15];
  const float* fcW = (const float*)d_in[16];
  const float* fcb = (const float*)d_in[17];
  float* out = (float*)d_out;

  char* ws = (char*)d_ws;
  size_t off = 0;
  auto carve = [&](size_t bytes) {
    void* p = ws + off;
    off += (bytes + 255) & ~(size_t)255;
    return p;
  };
  short* wc_e0 = (short*)carve(4096l * 1280 * 2);
  short* wc_e1 = (short*)carve(4096l * 2048 * 2);
  short* wc_d0 = (short*)carve(4096l * 1280 * 2);
  short* wc_d1 = (short*)carve(4096l * 2048 * 2);
  short* fcwt = (short*)carve(256l * 1024 * 2);
  short* embe = (short*)carve(256l * 256 * 2);
  short* embd = (short*)carve(256l * 256 * 2);
  short* xe0 = (short*)carve(2l * 1024 * 1280 * 2);
  short* xe1 = (short*)carve(2l * 1024 * 2048 * 2);
  short* xd0 = (short*)carve(2l * 1024 * 1280 * 2);
  short* xd1 = (short*)carve(2l * 1024 * 2048 * 2);
  short* dh1 = (short*)carve(47l * 1024 * 1024 * 2);
  const size_t flagbytes = 2l * 79 * 8 * 32 * 4;
  unsigned* flags = (unsigned*)carve(flagbytes);

  hipMemsetAsync(flags, 0, flagbytes, stream);
  hipMemsetAsync(out, 0, 1024l * 256 * 4, stream);  // outputs[0] stays zeros

  wprep<<<2560, 256, 0, stream>>>(eW0i, eW0h, wc_e0, 4096, 256, 1024);
  wprep<<<4096, 256, 0, stream>>>(eW1i, eW1h, wc_e1, 4096, 1024, 1024);
  wprep<<<2560, 256, 0, stream>>>(dW0i, dW0h, wc_d0, 4096, 256, 1024);
  wprep<<<4096, 256, 0, stream>>>(dW1i, dW1h, wc_d1, 4096, 1024, 1024);
  embprep<<<32, 256, 0, stream>>>(enc_emb, embe, 8192);
  embprep<<<32, 256, 0, stream>>>(dec_emb, embd, 8192);
  fcwprep<<<128, 256, 0, stream>>>(fcW, fcwt);
  initk<<<1152, 256, 0, stream>>>(src, enc_emb, xe0, xe1);

  pers_kernel<<<512, 256, 0, stream>>>(
      xe0, xe1, xd0, xd1, wc_e0, wc_e1, wc_d0, wc_d1,
      eb0, eb1, db0, db1, embe, embd, src, tgt, dh1, flags);

  fc_kernel<<<dim3(2, 376), 256, 0, stream>>>(dh1, fcwt, fcb, out + 1024l * 256);
}

// Round 11
// 4207.141 us; speedup vs baseline: 1.1967x; 1.0024x over previous
//
#include <hip/hip_runtime.h>
#include <hip/hip_fp16.h>

typedef __attribute__((ext_vector_type(8))) short short8;
typedef __attribute__((ext_vector_type(4))) float floatx4;

#define DEVFN static __device__ __forceinline__

DEVFN short f2h(float v) { return __half_as_short(__float2half(v)); }

DEVFN void gload16(const void* g, void* l) {
  void* gnc = const_cast<void*>(g);
  __builtin_amdgcn_global_load_lds(
      (__attribute__((address_space(1))) void*)gnc,
      (__attribute__((address_space(3))) void*)l, 16, 0, 0);
}

// flag set for (role, s, gy): 32 cells, one per u-tile block
DEVFN unsigned* fset(unsigned* f, int role, int s, int gy) {
  return f + ((((role * 79) + s) * 8 + gy) << 5);
}

// Persistent dataflow kernel, SLACK-3: activation buffers are triple-slotted
// (slot = t%3), giving minimal dependency set
//   L0(s) <- L0(s-1), L1(s-3)   (anti-dep on the x-half slot L1(s-3) read)
//   L1(s) <- L0(s),  L1(s-1)
// so the L0 chain free-runs up to 3 steps ahead and producer jitter
// decorrelates (no per-step max-of-32 convoy).
// K-loop: R7-proven (K=64, 2 LDS buffers, syncthreads).
// T1: XCD-aware flat-grid decode — XCD owns a 128-unit superblock; per-XCD W
// working set 3.4 MB < 4 MB L2.
__global__ __launch_bounds__(256, 2) void pers_kernel(
    short* xe0, short* xe1, short* xd0, short* xd1,
    const short* wc_e0, const short* wc_e1, const short* wc_d0, const short* wc_d1,
    const float* eb0, const float* eb1, const float* db0, const float* db1,
    const short* embe, const short* embd,
    const int* __restrict__ src, const int* __restrict__ tgt,
    short* dh1, unsigned* flags) {
  __shared__ short smem[32768];  // 2 buffers x (A 128x64 | W 128x64) fp16 = 64 KB
  const int tid = threadIdx.x;
  const int lane = tid & 63;
  const int wv = tid >> 6;   // 0..3
  const int wm = wv >> 1;    // 64-row group
  const int wu = wv & 1;     // 16-unit group
  const int l15 = lane & 15;
  const int l4 = lane >> 4;
  // ---- XCD-aware decode: xcd = bid%8 (HW round-robin), owns 4 u-tiles ----
  const int bid = blockIdx.x;          // 0..511
  const int xcd = bid & 7;
  const int idx = bid >> 3;            // 0..63 within XCD
  const int role1 = idx >> 5;          // 0 = L0, 1 = L1
  const int rem = idx & 31;
  const int ut = xcd * 4 + (rem >> 3); // 0..31 unit tile (32 units)
  const int gy = rem & 7;              // batch group
  const int u0 = ut * 32;
  const int m0 = gy * 128;
  const int srow = lane >> 3;
  const int swseg = ((lane & 7) * 16) ^ (srow * 16);  // source-side LDS swizzle
  const long SL0 = 1024l * 1280, SL1 = 1024l * 2048;

  float cst[16];
#pragma unroll
  for (int i = 0; i < 16; ++i) cst[i] = 0.f;

  for (int s = 0; s < 79; ++s) {
    // ---- dependency wait (wave-0 lanes poll producer cells) ----
    unsigned* WA = nullptr;
    unsigned* WB = nullptr;
    if (!role1) {
      if (s >= 1) WA = fset(flags, 0, s - 1, gy);
      if (s >= 3) WB = fset(flags, 1, s - 3, gy);   // slack-3 anti-dep
    } else {
      WA = fset(flags, 0, s, gy);
      if (s >= 1) WB = fset(flags, 1, s - 1, gy);
    }
    if (WA || WB) {
      if (tid < 64) {
        unsigned* p = (tid < 32) ? (WA ? WA + tid : nullptr)
                                 : (WB ? WB + (tid - 32) : nullptr);
        if (p) {
          while (__hip_atomic_load(p, __ATOMIC_RELAXED,
                                   __HIP_MEMORY_SCOPE_AGENT) == 0u)
            __builtin_amdgcn_s_sleep(1);
          (void)__hip_atomic_load(p, __ATOMIC_ACQUIRE, __HIP_MEMORY_SCOPE_AGENT);
        }
      }
      __syncthreads();
    }

    // ---- step params (3-slot rotation) ----
    const int enc = (s < 32) ? 1 : 0;
    const int t = enc ? s : s - 32;          // dec t = 0..46
    const int cur = t % 3, nxt = (t + 1) % 3;
    const short* A; const short* Wt; const float* bs; int ktot;
    short *d1 = nullptr, *d2 = nullptr, *d3 = nullptr, *xq = nullptr;
    int s1 = 0, o1 = 0, xs = 0;
    const short* xe = nullptr; const int* tk = nullptr;
    if (!role1) {
      if (enc) {
        A = xe0 + cur * SL0; Wt = wc_e0; bs = eb0; ktot = 1280;
        d2 = xe1 + cur * SL1;                 // h0(t) -> enc L1 input x-half
        s1 = 1280; o1 = 256; xs = 1280;
        if (t < 31) { d1 = xe0 + nxt * SL0; xq = d1; xe = embe; tk = src + (t + 1) * 1024; }
        else        { d1 = xd0;             xq = xd0; xe = embd; tk = tgt; }  // -> dec slot 0
      } else {
        A = xd0 + cur * SL0; Wt = wc_d0; bs = db0; ktot = 1280;
        d1 = xd0 + nxt * SL0; s1 = 1280; o1 = 256;
        d2 = xd1 + cur * SL1;                 // h0 -> dec L1 input x-half
        if (t < 46) { xq = xd0 + nxt * SL0; xs = 1280; xe = embd; tk = tgt + (t + 1) * 1024; }
      }
    } else {
      if (enc) {
        A = xe1 + cur * SL1; Wt = wc_e1; bs = eb1; ktot = 2048;
        d1 = (t < 31) ? (xe1 + nxt * SL1) : xd1; s1 = 2048; o1 = 1024;  // -> dec slot 0
      } else {
        A = xd1 + cur * SL1; Wt = wc_d1; bs = db1; ktot = 2048;
        d1 = xd1 + nxt * SL1; s1 = 2048; o1 = 1024;
        d3 = dh1 + (long)t * 1024 * 1024;     // archive dh1[t] (s=1024,o=0)
      }
    }

    // ---- GEMM: z = A @ W^T, 2-buffer LDS pipeline (R7-proven) ----
    floatx4 acc[4][4];
#pragma unroll
    for (int g = 0; g < 4; ++g)
#pragma unroll
      for (int mi = 0; mi < 4; ++mi) acc[g][mi] = (floatx4){0.f, 0.f, 0.f, 0.f};

    const char* Ab = (const char*)A;
    const char* Wb = (const char*)Wt;
    const long kbytes = (long)ktot * 2;
    const int nkb = ktot >> 6;

    auto stage = [&](int kb, int bufi) {
      const long kboff = (long)kb * 128;
      short* sb = smem + bufi * 16384;
#pragma unroll
      for (int ci = 0; ci < 8; ++ci) {
        const int c = wv * 8 + ci;
        void* lds = (void*)(sb + c * 512);
        if (c < 16) {  // A chunks
          const int row = c * 8 + srow;
          gload16(Ab + (long)(m0 + row) * kbytes + kboff + swseg, lds);
        } else {       // W chunks: 4 gates x 32 units
          const int cb = c - 16;
          const int wrow = (cb >> 2) * 1024 + u0 + (cb & 3) * 8 + srow;
          gload16(Wb + (long)wrow * kbytes + kboff + swseg, lds);
        }
      }
    };

    stage(0, 0);
    __syncthreads();
    int buf = 0;
    for (int kb = 0; kb < nkb; ++kb) {
      if (kb + 1 < nkb) stage(kb + 1, buf ^ 1);  // prefetch under compute
      const short* sb = smem + buf * 16384;
#pragma unroll
      for (int k0 = 0; k0 < 64; k0 += 32) {
        short8 fa[4];
        short8 fb[4];
#pragma unroll
        for (int mi = 0; mi < 4; ++mi) {
          const int r = wm * 64 + mi * 16 + l15;
          fa[mi] = *(const short8*)(sb + r * 64 + ((k0 + l4 * 8) ^ ((r & 7) << 3)));
        }
        {
          const int r = wu * 16 + l15;
          const int kk = (k0 + l4 * 8) ^ ((r & 7) << 3);
#pragma unroll
          for (int g = 0; g < 4; ++g)
            fb[g] = *(const short8*)(sb + 8192 + (g * 32 + r) * 64 + kk);
        }
#pragma unroll
        for (int g = 0; g < 4; ++g)
#pragma unroll
          for (int mi = 0; mi < 4; ++mi)
            asm volatile("v_mfma_f32_16x16x32_f16 %0, %1, %2, %0"
                         : "+v"(acc[g][mi])
                         : "v"(fa[mi]), "v"(fb[g]));
      }
      __syncthreads();
      buf ^= 1;
    }
    asm volatile("s_nop 7\ns_nop 7\ns_nop 7");  // MFMA -> VALU hazard guard

    // ---- LSTM cell (c in regs) -> h into LDS transpose tile ----
    const int u = u0 + wu * 16 + l15;
    const float bi = bs[u];
    const float bf_ = bs[1024 + u];
    const float bg = bs[2048 + u];
    const float bo = bs[3072 + u];
    short* ht = smem;  // [128][40] fp16, reuses buf0 (all LDS reads done)
    const int uloc = wu * 16 + l15;
#pragma unroll
    for (int mi = 0; mi < 4; ++mi) {
#pragma unroll
      for (int j = 0; j < 4; ++j) {
        const float zi = acc[0][mi][j] + bi;
        const float zf = acc[1][mi][j] + bf_;
        const float zg = acc[2][mi][j] + bg;
        const float zo = acc[3][mi][j] + bo;
        const float gi = 1.f / (1.f + expf(-zi));
        const float gf = 1.f / (1.f + expf(-zf));
        const float gg = tanhf(zg);
        const float go = 1.f / (1.f + expf(-zo));
        const float cn = gf * cst[mi * 4 + j] + gi * gg;
        cst[mi * 4 + j] = cn;
        const int rl = wm * 64 + mi * 16 + l4 * 4 + j;
        ht[rl * 40 + uloc] = f2h(go * tanhf(cn));
      }
    }
    __syncthreads();

    // ---- coalesced h writes (32 B/thread per dest) ----
    {
      const int rl = tid >> 1;
      const int seg = (tid & 1) * 16;
      const short8 v0 = *(const short8*)(ht + rl * 40 + seg);
      const short8 v1 = *(const short8*)(ht + rl * 40 + seg + 8);
      const long col = u0 + seg;
      if (d1) {
        short* p = d1 + (long)(m0 + rl) * s1 + o1 + col;
        *(short8*)p = v0; *(short8*)(p + 8) = v1;
      }
      if (d2) {
        short* p = d2 + (long)(m0 + rl) * 2048 + col;
        *(short8*)p = v0; *(short8*)(p + 8) = v1;
      }
      if (d3) {
        short* p = d3 + (long)(m0 + rl) * 1024 + col;
        *(short8*)p = v0; *(short8*)(p + 8) = v1;
      }
    }
    // ---- next-step embedding gather: 128-item slice per L0 block ----
    if (xq && tid < 128) {
      const int i = ut * 128 + tid;
      const int row = i >> 5;
      const int e8 = (i & 31) * 8;
      const int b = m0 + row;
      const int tok = tk[b];
      const short8 v = *(const short8*)(xe + (long)tok * 256 + e8);
      *(short8*)(xq + (long)b * xs + e8) = v;
    }

    // ---- publish: all stores drained (syncthreads), then release flag ----
    __syncthreads();
    if (tid == 0)
      __hip_atomic_store(fset(flags, role1, s, gy) + ut, 1u,
                         __ATOMIC_RELEASE, __HIP_MEMORY_SCOPE_AGENT);
  }
}

// fc projection: out[1:] = dh1_all @ fcWt^T + fc_b
__global__ __launch_bounds__(256) void fc_kernel(
    const short* __restrict__ A, const short* __restrict__ W,
    const float* __restrict__ bias, float* __restrict__ outp) {
  __shared__ short smem[32768];
  const int tid = threadIdx.x;
  const int lane = tid & 63;
  const int wv = tid >> 6;
  const int wm = wv >> 1;
  const int wu = wv & 1;
  const int l15 = lane & 15;
  const int l4 = lane >> 4;
  const int u0 = blockIdx.x * 128;
  const int m0 = blockIdx.y * 128;
  const int srow = lane >> 3;
  const int swseg = ((lane & 7) * 16) ^ (srow * 16);

  floatx4 acc[4][4];
#pragma unroll
  for (int g = 0; g < 4; ++g)
#pragma unroll
    for (int mi = 0; mi < 4; ++mi) acc[g][mi] = (floatx4){0.f, 0.f, 0.f, 0.f};

  const char* Ab = (const char*)A;
  const char* Wb = (const char*)W;
  const long kbytes = 2048;
  const int nkb = 16;

  auto stage = [&](int kb, int bufi) {
    const long kboff = (long)kb * 128;
    short* sb = smem + bufi * 16384;
#pragma unroll
    for (int ci = 0; ci < 8; ++ci) {
      const int c = wv * 8 + ci;
      void* lds = (void*)(sb + c * 512);
      if (c < 16) {
        const int row = c * 8 + srow;
        gload16(Ab + (long)(m0 + row) * kbytes + kboff + swseg, lds);
      } else {
        const int cb = c - 16;
        const int wrow = (cb >> 2) * 32 + u0 + (cb & 3) * 8 + srow;
        gload16(Wb + (long)wrow * kbytes + kboff + swseg, lds);
      }
    }
  };

  stage(0, 0);
  __syncthreads();
  int buf = 0;
  for (int kb = 0; kb < nkb; ++kb) {
    if (kb + 1 < nkb) stage(kb + 1, buf ^ 1);
    const short* sb = smem + buf * 16384;
#pragma unroll
    for (int k0 = 0; k0 < 64; k0 += 32) {
      short8 fa[4];
      short8 fb[4];
#pragma unroll
      for (int mi = 0; mi < 4; ++mi) {
        const int r = wm * 64 + mi * 16 + l15;
        fa[mi] = *(const short8*)(sb + r * 64 + ((k0 + l4 * 8) ^ ((r & 7) << 3)));
      }
      {
        const int r = wu * 16 + l15;
        const int kk = (k0 + l4 * 8) ^ ((r & 7) << 3);
#pragma unroll
        for (int g = 0; g < 4; ++g)
          fb[g] = *(const short8*)(sb + 8192 + (g * 32 + r) * 64 + kk);
      }
#pragma unroll
      for (int g = 0; g < 4; ++g)
#pragma unroll
        for (int mi = 0; mi < 4; ++mi)
          asm volatile("v_mfma_f32_16x16x32_f16 %0, %1, %2, %0"
                       : "+v"(acc[g][mi])
                       : "v"(fa[mi]), "v"(fb[g]));
    }
    __syncthreads();
    buf ^= 1;
  }
  asm volatile("s_nop 7\ns_nop 7\ns_nop 7");

#pragma unroll
  for (int g = 0; g < 4; ++g) {
    const int n = u0 + g * 32 + wu * 16 + l15;
    const float bb = bias[n];
#pragma unroll
    for (int mi = 0; mi < 4; ++mi) {
#pragma unroll
      for (int j = 0; j < 4; ++j) {
        const int r = m0 + wm * 64 + mi * 16 + l4 * 4 + j;
        outp[(long)r * 256 + n] = acc[g][mi][j] + bb;
      }
    }
  }
}

// weights -> fp16, [Wih | Whh] concat along K, gate-major rows, LINEAR layout
__global__ void wprep(const float* __restrict__ A, const float* __restrict__ B,
                      short* __restrict__ dst, int N, int Ka, int Kb) {
  const int ktot = Ka + Kb;
  const int n8 = ktot >> 3;
  const int total = N * n8;
  for (int idx = blockIdx.x * 256 + threadIdx.x; idx < total; idx += gridDim.x * 256) {
    const int n = idx / n8;
    const int k = (idx - n * n8) * 8;
    const float* s = (k < Ka) ? (A + (long)n * Ka + k) : (B + (long)n * Kb + (k - Ka));
    short8 v;
#pragma unroll
    for (int j = 0; j < 8; ++j) v[j] = f2h(s[j]);
    *(short8*)(dst + (long)n * ktot + k) = v;
  }
}

__global__ void embprep(const float* __restrict__ s, short* __restrict__ d, int total8) {
  const int idx = blockIdx.x * 256 + threadIdx.x;
  if (idx >= total8) return;
  short8 v;
#pragma unroll
  for (int j = 0; j < 8; ++j) v[j] = f2h(s[idx * 8 + j]);
  *(short8*)(d + idx * 8) = v;
}

// fc_W [1024][256] -> fcWt [256][1024] fp16, LINEAR
__global__ void fcwprep(const float* __restrict__ fcW, short* __restrict__ dst) {
  const int idx = blockIdx.x * 256 + threadIdx.x;  // 32768
  const int v = idx & 255;
  const int h = (idx >> 8) * 8;
  short8 o;
#pragma unroll
  for (int j = 0; j < 8; ++j) o[j] = f2h(fcW[(long)(h + j) * 256 + v]);
  *(short8*)(dst + (long)v * 1024 + h) = o;
}

// xe0 slot0: x = enc_emb[src[0]], h = 0 ; xe1 slot0 h-half = 0   (LINEAR)
__global__ void initk(const int* __restrict__ src, const float* __restrict__ emb,
                      short* __restrict__ xe0, short* __restrict__ xe1) {
  const int idx = blockIdx.x * 256 + threadIdx.x;
  if (idx < 1024 * 160) {
    const int b = idx / 160;
    const int k = (idx - b * 160) * 8;
    short8 v;
    if (k < 256) {
      const int tok = src[b];
#pragma unroll
      for (int j = 0; j < 8; ++j) v[j] = f2h(emb[(long)tok * 256 + k + j]);
    } else {
#pragma unroll
      for (int j = 0; j < 8; ++j) v[j] = 0;
    }
    *(short8*)(xe0 + (long)b * 1280 + k) = v;
  } else {
    const int i = idx - 1024 * 160;
    if (i < 1024 * 128) {
      const int b = i >> 7;
      const int k = 1024 + (i & 127) * 8;
      short8 v;
#pragma unroll
      for (int j = 0; j < 8; ++j) v[j] = 0;
      *(short8*)(xe1 + (long)b * 2048 + k) = v;
    }
  }
}

extern "C" void kernel_launch(void* const* d_in, const int* in_sizes, int n_in,
                              void* d_out, int out_size, void* d_ws, size_t ws_size,
                              hipStream_t stream) {
  (void)in_sizes; (void)n_in; (void)out_size; (void)ws_size;
  const int* src = (const int*)d_in[0];
  const int* tgt = (const int*)d_in[1];
  const float* enc_emb = (const float*)d_in[2];
  const float* eW0i = (const float*)d_in[3];
  const float* eW0h = (const float*)d_in[4];
  const float* eb0 = (const float*)d_in[5];
  const float* eW1i = (const float*)d_in[6];
  const float* eW1h = (const float*)d_in[7];
  const float* eb1 = (const float*)d_in[8];
  const float* dec_emb = (const float*)d_in[9];
  const float* dW0i = (const float*)d_in[10];
  const float* dW0h = (const float*)d_in[11];
  const float* db0 = (const float*)d_in[12];
  const float* dW1i = (const float*)d_in[13];
  const float* dW1h = (const float*)d_in[14];
  const float* db1 = (const float*)d_in[15];
  const float* fcW = (const float*)d_in[16];
  const float* fcb = (const float*)d_in[17];
  float* out = (float*)d_out;

  char* ws = (char*)d_ws;
  size_t off = 0;
  auto carve = [&](size_t bytes) {
    void* p = ws + off;
    off += (bytes + 255) & ~(size_t)255;
    return p;
  };
  short* wc_e0 = (short*)carve(4096l * 1280 * 2);
  short* wc_e1 = (short*)carve(4096l * 2048 * 2);
  short* wc_d0 = (short*)carve(4096l * 1280 * 2);
  short* wc_d1 = (short*)carve(4096l * 2048 * 2);
  short* fcwt = (short*)carve(256l * 1024 * 2);
  short* embe = (short*)carve(256l * 256 * 2);
  short* embd = (short*)carve(256l * 256 * 2);
  short* xe0 = (short*)carve(3l * 1024 * 1280 * 2);   // 3 slots (slack-3)
  short* xe1 = (short*)carve(3l * 1024 * 2048 * 2);
  short* xd0 = (short*)carve(3l * 1024 * 1280 * 2);
  short* xd1 = (short*)carve(3l * 1024 * 2048 * 2);
  short* dh1 = (short*)carve(47l * 1024 * 1024 * 2);
  const size_t flagbytes = 2l * 79 * 8 * 32 * 4;
  unsigned* flags = (unsigned*)carve(flagbytes);

  hipMemsetAsync(flags, 0, flagbytes, stream);
  hipMemsetAsync(out, 0, 1024l * 256 * 4, stream);  // outputs[0] stays zeros

  wprep<<<2560, 256, 0, stream>>>(eW0i, eW0h, wc_e0, 4096, 256, 1024);
  wprep<<<4096, 256, 0, stream>>>(eW1i, eW1h, wc_e1, 4096, 1024, 1024);
  wprep<<<2560, 256, 0, stream>>>(dW0i, dW0h, wc_d0, 4096, 256, 1024);
  wprep<<<4096, 256, 0, stream>>>(dW1i, dW1h, wc_d1, 4096, 1024, 1024);
  embprep<<<32, 256, 0, stream>>>(enc_emb, embe, 8192);
  embprep<<<32, 256, 0, stream>>>(dec_emb, embd, 8192);
  fcwprep<<<128, 256, 0, stream>>>(fcW, fcwt);
  initk<<<1152, 256, 0, stream>>>(src, enc_emb, xe0, xe1);

  pers_kernel<<<512, 256, 0, stream>>>(
      xe0, xe1, xd0, xd1, wc_e0, wc_e1, wc_d0, wc_d1,
      eb0, eb1, db0, db1, embe, embd, src, tgt, dh1, flags);

  fc_kernel<<<dim3(2, 376), 256, 0, stream>>>(dh1, fcwt, fcb, out + 1024l * 256);
}

// Round 12
// 3999.226 us; speedup vs baseline: 1.2589x; 1.0520x over previous
//
#include <hip/hip_runtime.h>
#include <hip/hip_fp16.h>

typedef __attribute__((ext_vector_type(8))) short short8;
typedef __attribute__((ext_vector_type(4))) float floatx4;

#define DEVFN static __device__ __forceinline__

DEVFN short f2h(float v) { return __half_as_short(__float2half(v)); }

DEVFN void gload16(const void* g, void* l) {
  void* gnc = const_cast<void*>(g);
  __builtin_amdgcn_global_load_lds(
      (__attribute__((address_space(1))) void*)gnc,
      (__attribute__((address_space(3))) void*)l, 16, 0, 0);
}

// flag set for (role, s, gy): 32 cells, one per u-tile block
DEVFN unsigned* fset(unsigned* f, int role, int s, int gy) {
  return f + ((((role * 79) + s) * 8 + gy) << 5);
}

// Persistent dataflow kernel, slack-3 (slot = t%3):
//   L0(s) <- L0(s-1), L1(s-3);   L1(s) <- L0(s), L1(s-1)
// NEW: 512 threads = 8 waves/block (wave tile 32 rows x 16 units, acc[4][2]),
// 2 blocks/CU -> 16 waves/CU (4/SIMD) to hide the per-kb staging-drain and
// cross-XCD L3 latency. K-loop: K=64, 2 LDS buffers, syncthreads (R7-proven).
// T1: XCD-aware flat-grid decode — per-XCD W working set 3.4 MB < 4 MB L2.
__global__ __launch_bounds__(512, 4) void pers_kernel(
    short* xe0, short* xe1, short* xd0, short* xd1,
    const short* wc_e0, const short* wc_e1, const short* wc_d0, const short* wc_d1,
    const float* eb0, const float* eb1, const float* db0, const float* db1,
    const short* embe, const short* embd,
    const int* __restrict__ src, const int* __restrict__ tgt,
    short* dh1, unsigned* flags) {
  __shared__ short smem[32768];  // 2 buffers x (A 128x64 | W 128x64) fp16 = 64 KB
  const int tid = threadIdx.x;
  const int lane = tid & 63;
  const int wv = tid >> 6;   // 0..7
  const int wm = wv >> 1;    // 0..3 : 32-row group
  const int wu = wv & 1;     // 16-unit group
  const int l15 = lane & 15;
  const int l4 = lane >> 4;
  // ---- XCD-aware decode: xcd = bid%8 (HW round-robin), owns 4 u-tiles ----
  const int bid = blockIdx.x;          // 0..511
  const int xcd = bid & 7;
  const int idx = bid >> 3;            // 0..63 within XCD
  const int role1 = idx >> 5;          // 0 = L0, 1 = L1
  const int rem = idx & 31;
  const int ut = xcd * 4 + (rem >> 3); // 0..31 unit tile (32 units)
  const int gy = rem & 7;              // batch group
  const int u0 = ut * 32;
  const int m0 = gy * 128;
  const int srow = lane >> 3;
  const int swseg = ((lane & 7) * 16) ^ (srow * 16);  // source-side LDS swizzle
  const long SL0 = 1024l * 1280, SL1 = 1024l * 2048;

  float cst[8];
#pragma unroll
  for (int i = 0; i < 8; ++i) cst[i] = 0.f;

  for (int s = 0; s < 79; ++s) {
    // ---- dependency wait (wave-0 lanes poll producer cells) ----
    unsigned* WA = nullptr;
    unsigned* WB = nullptr;
    if (!role1) {
      if (s >= 1) WA = fset(flags, 0, s - 1, gy);
      if (s >= 3) WB = fset(flags, 1, s - 3, gy);   // slack-3 anti-dep
    } else {
      WA = fset(flags, 0, s, gy);
      if (s >= 1) WB = fset(flags, 1, s - 1, gy);
    }
    if (WA || WB) {
      if (tid < 64) {
        unsigned* p = (tid < 32) ? (WA ? WA + tid : nullptr)
                                 : (WB ? WB + (tid - 32) : nullptr);
        if (p) {
          while (__hip_atomic_load(p, __ATOMIC_RELAXED,
                                   __HIP_MEMORY_SCOPE_AGENT) == 0u)
            __builtin_amdgcn_s_sleep(1);
          (void)__hip_atomic_load(p, __ATOMIC_ACQUIRE, __HIP_MEMORY_SCOPE_AGENT);
        }
      }
      __syncthreads();
    }

    // ---- step params (3-slot rotation) ----
    const int enc = (s < 32) ? 1 : 0;
    const int t = enc ? s : s - 32;          // dec t = 0..46
    const int cur = t % 3, nxt = (t + 1) % 3;
    const short* A; const short* Wt; const float* bs; int ktot;
    short *d1 = nullptr, *d2 = nullptr, *d3 = nullptr, *xq = nullptr;
    int s1 = 0, o1 = 0, xs = 0;
    const short* xe = nullptr; const int* tk = nullptr;
    if (!role1) {
      if (enc) {
        A = xe0 + cur * SL0; Wt = wc_e0; bs = eb0; ktot = 1280;
        d2 = xe1 + cur * SL1;                 // h0(t) -> enc L1 input x-half
        s1 = 1280; o1 = 256; xs = 1280;
        if (t < 31) { d1 = xe0 + nxt * SL0; xq = d1; xe = embe; tk = src + (t + 1) * 1024; }
        else        { d1 = xd0;             xq = xd0; xe = embd; tk = tgt; }  // -> dec slot 0
      } else {
        A = xd0 + cur * SL0; Wt = wc_d0; bs = db0; ktot = 1280;
        d1 = xd0 + nxt * SL0; s1 = 1280; o1 = 256;
        d2 = xd1 + cur * SL1;                 // h0 -> dec L1 input x-half
        if (t < 46) { xq = xd0 + nxt * SL0; xs = 1280; xe = embd; tk = tgt + (t + 1) * 1024; }
      }
    } else {
      if (enc) {
        A = xe1 + cur * SL1; Wt = wc_e1; bs = eb1; ktot = 2048;
        d1 = (t < 31) ? (xe1 + nxt * SL1) : xd1; s1 = 2048; o1 = 1024;  // -> dec slot 0
      } else {
        A = xd1 + cur * SL1; Wt = wc_d1; bs = db1; ktot = 2048;
        d1 = xd1 + nxt * SL1; s1 = 2048; o1 = 1024;
        d3 = dh1 + (long)t * 1024 * 1024;     // archive dh1[t] (s=1024,o=0)
      }
    }

    // ---- GEMM: z = A @ W^T, 2-buffer LDS pipeline ----
    floatx4 acc[4][2];
#pragma unroll
    for (int g = 0; g < 4; ++g)
#pragma unroll
      for (int mi = 0; mi < 2; ++mi) acc[g][mi] = (floatx4){0.f, 0.f, 0.f, 0.f};

    const char* Ab = (const char*)A;
    const char* Wb = (const char*)Wt;
    const long kbytes = (long)ktot * 2;
    const int nkb = ktot >> 6;

    auto stage = [&](int kb, int bufi) {
      const long kboff = (long)kb * 128;
      short* sb = smem + bufi * 16384;
#pragma unroll
      for (int ci = 0; ci < 4; ++ci) {
        const int c = wv * 4 + ci;          // 32 chunks over 8 waves
        void* lds = (void*)(sb + c * 512);
        if (c < 16) {  // A chunks: rows c*8..c*8+8
          const int row = c * 8 + srow;
          gload16(Ab + (long)(m0 + row) * kbytes + kboff + swseg, lds);
        } else {       // W chunks: 4 gates x 32 units
          const int cb = c - 16;
          const int wrow = (cb >> 2) * 1024 + u0 + (cb & 3) * 8 + srow;
          gload16(Wb + (long)wrow * kbytes + kboff + swseg, lds);
        }
      }
    };

    stage(0, 0);
    __syncthreads();
    int buf = 0;
    for (int kb = 0; kb < nkb; ++kb) {
      if (kb + 1 < nkb) stage(kb + 1, buf ^ 1);  // prefetch under compute
      const short* sb = smem + buf * 16384;
#pragma unroll
      for (int k0 = 0; k0 < 64; k0 += 32) {
        short8 fa[2];
        short8 fb[4];
#pragma unroll
        for (int mi = 0; mi < 2; ++mi) {
          const int r = wm * 32 + mi * 16 + l15;
          fa[mi] = *(const short8*)(sb + r * 64 + ((k0 + l4 * 8) ^ ((r & 7) << 3)));
        }
        {
          const int r = wu * 16 + l15;
          const int kk = (k0 + l4 * 8) ^ ((r & 7) << 3);
#pragma unroll
          for (int g = 0; g < 4; ++g)
            fb[g] = *(const short8*)(sb + 8192 + (g * 32 + r) * 64 + kk);
        }
#pragma unroll
        for (int g = 0; g < 4; ++g)
#pragma unroll
          for (int mi = 0; mi < 2; ++mi)
            asm volatile("v_mfma_f32_16x16x32_f16 %0, %1, %2, %0"
                         : "+v"(acc[g][mi])
                         : "v"(fa[mi]), "v"(fb[g]));
      }
      __syncthreads();
      buf ^= 1;
    }
    asm volatile("s_nop 7\ns_nop 7\ns_nop 7");  // MFMA -> VALU hazard guard

    // ---- LSTM cell (c in regs) -> h into LDS transpose tile ----
    const int u = u0 + wu * 16 + l15;
    const float bi = bs[u];
    const float bf_ = bs[1024 + u];
    const float bg = bs[2048 + u];
    const float bo = bs[3072 + u];
    short* ht = smem;  // [128][40] fp16, reuses buf0 (all LDS reads done)
    const int uloc = wu * 16 + l15;
#pragma unroll
    for (int mi = 0; mi < 2; ++mi) {
#pragma unroll
      for (int j = 0; j < 4; ++j) {
        const float zi = acc[0][mi][j] + bi;
        const float zf = acc[1][mi][j] + bf_;
        const float zg = acc[2][mi][j] + bg;
        const float zo = acc[3][mi][j] + bo;
        const float gi = 1.f / (1.f + expf(-zi));
        const float gf = 1.f / (1.f + expf(-zf));
        const float gg = tanhf(zg);
        const float go = 1.f / (1.f + expf(-zo));
        const float cn = gf * cst[mi * 4 + j] + gi * gg;
        cst[mi * 4 + j] = cn;
        const int rl = wm * 32 + mi * 16 + l4 * 4 + j;
        ht[rl * 40 + uloc] = f2h(go * tanhf(cn));
      }
    }
    __syncthreads();

    // ---- coalesced h writes (16 B/thread per dest) ----
    {
      const int rl = tid >> 2;
      const int seg = (tid & 3) * 8;
      const short8 v = *(const short8*)(ht + rl * 40 + seg);
      const long col = u0 + seg;
      if (d1) *(short8*)(d1 + (long)(m0 + rl) * s1 + o1 + col) = v;
      if (d2) *(short8*)(d2 + (long)(m0 + rl) * 2048 + col) = v;
      if (d3) *(short8*)(d3 + (long)(m0 + rl) * 1024 + col) = v;
    }
    // ---- next-step embedding gather: 128-item slice per L0 block ----
    if (xq && tid < 128) {
      const int i = ut * 128 + tid;
      const int row = i >> 5;
      const int e8 = (i & 31) * 8;
      const int b = m0 + row;
      const int tok = tk[b];
      const short8 v = *(const short8*)(xe + (long)tok * 256 + e8);
      *(short8*)(xq + (long)b * xs + e8) = v;
    }

    // ---- publish: all stores drained (syncthreads), then release flag ----
    __syncthreads();
    if (tid == 0)
      __hip_atomic_store(fset(flags, role1, s, gy) + ut, 1u,
                         __ATOMIC_RELEASE, __HIP_MEMORY_SCOPE_AGENT);
  }
}

// fc projection: out[1:] = dh1_all @ fcWt^T + fc_b
__global__ __launch_bounds__(256) void fc_kernel(
    const short* __restrict__ A, const short* __restrict__ W,
    const float* __restrict__ bias, float* __restrict__ outp) {
  __shared__ short smem[32768];
  const int tid = threadIdx.x;
  const int lane = tid & 63;
  const int wv = tid >> 6;
  const int wm = wv >> 1;
  const int wu = wv & 1;
  const int l15 = lane & 15;
  const int l4 = lane >> 4;
  const int u0 = blockIdx.x * 128;
  const int m0 = blockIdx.y * 128;
  const int srow = lane >> 3;
  const int swseg = ((lane & 7) * 16) ^ (srow * 16);

  floatx4 acc[4][4];
#pragma unroll
  for (int g = 0; g < 4; ++g)
#pragma unroll
    for (int mi = 0; mi < 4; ++mi) acc[g][mi] = (floatx4){0.f, 0.f, 0.f, 0.f};

  const char* Ab = (const char*)A;
  const char* Wb = (const char*)W;
  const long kbytes = 2048;
  const int nkb = 16;

  auto stage = [&](int kb, int bufi) {
    const long kboff = (long)kb * 128;
    short* sb = smem + bufi * 16384;
#pragma unroll
    for (int ci = 0; ci < 8; ++ci) {
      const int c = wv * 8 + ci;
      void* lds = (void*)(sb + c * 512);
      if (c < 16) {
        const int row = c * 8 + srow;
        gload16(Ab + (long)(m0 + row) * kbytes + kboff + swseg, lds);
      } else {
        const int cb = c - 16;
        const int wrow = (cb >> 2) * 32 + u0 + (cb & 3) * 8 + srow;
        gload16(Wb + (long)wrow * kbytes + kboff + swseg, lds);
      }
    }
  };

  stage(0, 0);
  __syncthreads();
  int buf = 0;
  for (int kb = 0; kb < nkb; ++kb) {
    if (kb + 1 < nkb) stage(kb + 1, buf ^ 1);
    const short* sb = smem + buf * 16384;
#pragma unroll
    for (int k0 = 0; k0 < 64; k0 += 32) {
      short8 fa[4];
      short8 fb[4];
#pragma unroll
      for (int mi = 0; mi < 4; ++mi) {
        const int r = wm * 64 + mi * 16 + l15;
        fa[mi] = *(const short8*)(sb + r * 64 + ((k0 + l4 * 8) ^ ((r & 7) << 3)));
      }
      {
        const int r = wu * 16 + l15;
        const int kk = (k0 + l4 * 8) ^ ((r & 7) << 3);
#pragma unroll
        for (int g = 0; g < 4; ++g)
          fb[g] = *(const short8*)(sb + 8192 + (g * 32 + r) * 64 + kk);
      }
#pragma unroll
      for (int g = 0; g < 4; ++g)
#pragma unroll
        for (int mi = 0; mi < 4; ++mi)
          asm volatile("v_mfma_f32_16x16x32_f16 %0, %1, %2, %0"
                       : "+v"(acc[g][mi])
                       : "v"(fa[mi]), "v"(fb[g]));
    }
    __syncthreads();
    buf ^= 1;
  }
  asm volatile("s_nop 7\ns_nop 7\ns_nop 7");

#pragma unroll
  for (int g = 0; g < 4; ++g) {
    const int n = u0 + g * 32 + wu * 16 + l15;
    const float bb = bias[n];
#pragma unroll
    for (int mi = 0; mi < 4; ++mi) {
#pragma unroll
      for (int j = 0; j < 4; ++j) {
        const int r = m0 + wm * 64 + mi * 16 + l4 * 4 + j;
        outp[(long)r * 256 + n] = acc[g][mi][j] + bb;
      }
    }
  }
}

// weights -> fp16, [Wih | Whh] concat along K, gate-major rows, LINEAR layout
__global__ void wprep(const float* __restrict__ A, const float* __restrict__ B,
                      short* __restrict__ dst, int N, int Ka, int Kb) {
  const int ktot = Ka + Kb;
  const int n8 = ktot >> 3;
  const int total = N * n8;
  for (int idx = blockIdx.x * 256 + threadIdx.x; idx < total; idx += gridDim.x * 256) {
    const int n = idx / n8;
    const int k = (idx - n * n8) * 8;
    const float* s = (k < Ka) ? (A + (long)n * Ka + k) : (B + (long)n * Kb + (k - Ka));
    short8 v;
#pragma unroll
    for (int j = 0; j < 8; ++j) v[j] = f2h(s[j]);
    *(short8*)(dst + (long)n * ktot + k) = v;
  }
}

__global__ void embprep(const float* __restrict__ s, short* __restrict__ d, int total8) {
  const int idx = blockIdx.x * 256 + threadIdx.x;
  if (idx >= total8) return;
  short8 v;
#pragma unroll
  for (int j = 0; j < 8; ++j) v[j] = f2h(s[idx * 8 + j]);
  *(short8*)(d + idx * 8) = v;
}

// fc_W [1024][256] -> fcWt [256][1024] fp16, LINEAR
__global__ void fcwprep(const float* __restrict__ fcW, short* __restrict__ dst) {
  const int idx = blockIdx.x * 256 + threadIdx.x;  // 32768
  const int v = idx & 255;
  const int h = (idx >> 8) * 8;
  short8 o;
#pragma unroll
  for (int j = 0; j < 8; ++j) o[j] = f2h(fcW[(long)(h + j) * 256 + v]);
  *(short8*)(dst + (long)v * 1024 + h) = o;
}

// xe0 slot0: x = enc_emb[src[0]], h = 0 ; xe1 slot0 h-half = 0   (LINEAR)
__global__ void initk(const int* __restrict__ src, const float* __restrict__ emb,
                      short* __restrict__ xe0, short* __restrict__ xe1) {
  const int idx = blockIdx.x * 256 + threadIdx.x;
  if (idx < 1024 * 160) {
    const int b = idx / 160;
    const int k = (idx - b * 160) * 8;
    short8 v;
    if (k < 256) {
      const int tok = src[b];
#pragma unroll
      for (int j = 0; j < 8; ++j) v[j] = f2h(emb[(long)tok * 256 + k + j]);
    } else {
#pragma unroll
      for (int j = 0; j < 8; ++j) v[j] = 0;
    }
    *(short8*)(xe0 + (long)b * 1280 + k) = v;
  } else {
    const int i = idx - 1024 * 160;
    if (i < 1024 * 128) {
      const int b = i >> 7;
      const int k = 1024 + (i & 127) * 8;
      short8 v;
#pragma unroll
      for (int j = 0; j < 8; ++j) v[j] = 0;
      *(short8*)(xe1 + (long)b * 2048 + k) = v;
    }
  }
}

extern "C" void kernel_launch(void* const* d_in, const int* in_sizes, int n_in,
                              void* d_out, int out_size, void* d_ws, size_t ws_size,
                              hipStream_t stream) {
  (void)in_sizes; (void)n_in; (void)out_size; (void)ws_size;
  const int* src = (const int*)d_in[0];
  const int* tgt = (const int*)d_in[1];
  const float* enc_emb = (const float*)d_in[2];
  const float* eW0i = (const float*)d_in[3];
  const float* eW0h = (const float*)d_in[4];
  const float* eb0 = (const float*)d_in[5];
  const float* eW1i = (const float*)d_in[6];
  const float* eW1h = (const float*)d_in[7];
  const float* eb1 = (const float*)d_in[8];
  const float* dec_emb = (const float*)d_in[9];
  const float* dW0i = (const float*)d_in[10];
  const float* dW0h = (const float*)d_in[11];
  const float* db0 = (const float*)d_in[12];
  const float* dW1i = (const float*)d_in[13];
  const float* dW1h = (const float*)d_in[14];
  const float* db1 = (const float*)d_in[15];
  const float* fcW = (const float*)d_in[16];
  const float* fcb = (const float*)d_in[17];
  float* out = (float*)d_out;

  char* ws = (char*)d_ws;
  size_t off = 0;
  auto carve = [&](size_t bytes) {
    void* p = ws + off;
    off += (bytes + 255) & ~(size_t)255;
    return p;
  };
  short* wc_e0 = (short*)carve(4096l * 1280 * 2);
  short* wc_e1 = (short*)carve(4096l * 2048 * 2);
  short* wc_d0 = (short*)carve(4096l * 1280 * 2);
  short* wc_d1 = (short*)carve(4096l * 2048 * 2);
  short* fcwt = (short*)carve(256l * 1024 * 2);
  short* embe = (short*)carve(256l * 256 * 2);
  short* embd = (short*)carve(256l * 256 * 2);
  short* xe0 = (short*)carve(3l * 1024 * 1280 * 2);   // 3 slots (slack-3)
  short* xe1 = (short*)carve(3l * 1024 * 2048 * 2);
  short* xd0 = (short*)carve(3l * 1024 * 1280 * 2);
  short* xd1 = (short*)carve(3l * 1024 * 2048 * 2);
  short* dh1 = (short*)carve(47l * 1024 * 1024 * 2);
  const size_t flagbytes = 2l * 79 * 8 * 32 * 4;
  unsigned* flags = (unsigned*)carve(flagbytes);

  hipMemsetAsync(flags, 0, flagbytes, stream);
  hipMemsetAsync(out, 0, 1024l * 256 * 4, stream);  // outputs[0] stays zeros

  wprep<<<2560, 256, 0, stream>>>(eW0i, eW0h, wc_e0, 4096, 256, 1024);
  wprep<<<4096, 256, 0, stream>>>(eW1i, eW1h, wc_e1, 4096, 1024, 1024);
  wprep<<<2560, 256, 0, stream>>>(dW0i, dW0h, wc_d0, 4096, 256, 1024);
  wprep<<<4096, 256, 0, stream>>>(dW1i, dW1h, wc_d1, 4096, 1024, 1024);
  embprep<<<32, 256, 0, stream>>>(enc_emb, embe, 8192);
  embprep<<<32, 256, 0, stream>>>(dec_emb, embd, 8192);
  fcwprep<<<128, 256, 0, stream>>>(fcW, fcwt);
  initk<<<1152, 256, 0, stream>>>(src, enc_emb, xe0, xe1);

  pers_kernel<<<512, 512, 0, stream>>>(
      xe0, xe1, xd0, xd1, wc_e0, wc_e1, wc_d0, wc_d1,
      eb0, eb1, db0, db1, embe, embd, src, tgt, dh1, flags);

  fc_kernel<<<dim3(2, 376), 256, 0, stream>>>(dh1, fcwt, fcb, out + 1024l * 256);
}

// Round 13
// 3791.409 us; speedup vs baseline: 1.3279x; 1.0548x over previous
//
#include <hip/hip_runtime.h>
#include <hip/hip_fp16.h>

typedef __attribute__((ext_vector_type(8))) short short8;
typedef __attribute__((ext_vector_type(4))) float floatx4;

#define DEVFN static __device__ __forceinline__

DEVFN short f2h(float v) { return __half_as_short(__float2half(v)); }

DEVFN void gload16(const void* g, void* l) {
  void* gnc = const_cast<void*>(g);
  __builtin_amdgcn_global_load_lds(
      (__attribute__((address_space(1))) void*)gnc,
      (__attribute__((address_space(3))) void*)l, 16, 0, 0);
}

// flag set for (role, s, gy): 16 cells, one per 64-unit block
DEVFN unsigned* fset(unsigned* f, int role, int s, int gy) {
  return f + ((((role * 79) + s) * 8 + gy) << 4);
}

// Persistent dataflow kernel, slack-3 (slot = t%3):
//   L0(s) <- L0(s-1), L1(s-3);   L1(s) <- L0(s), L1(s-1)
// Block = 64 units x 128 rows (16 ut-blocks/role), 512 thr = 8 fat waves
// (64r x 16u x 4g, acc[4][4]). K-loop: K=64, THREE 48 KB LDS buffers
// (dynamic LDS 144 KB, 1 block/CU), prefetch depth 2, counted vmcnt(6) +
// raw s_barrier -> each stage has ~2 iterations in flight (L3 covered).
// T1: XCD owns a 128-unit superblock (2 ut4) -> W set 3.4 MB < 4 MB L2.
__global__ __launch_bounds__(512, 2) void pers_kernel(
    short* xe0, short* xe1, short* xd0, short* xd1,
    const short* wc_e0, const short* wc_e1, const short* wc_d0, const short* wc_d1,
    const float* eb0, const float* eb1, const float* db0, const float* db1,
    const short* embe, const short* embd,
    const int* __restrict__ src, const int* __restrict__ tgt,
    short* dh1, unsigned* flags) {
  extern __shared__ short smem[];  // 3 x 24576 shorts (48 KB: A 16K | W 32K)
  const int tid = threadIdx.x;
  const int lane = tid & 63;
  const int wv = tid >> 6;   // 0..7
  const int wm = wv >> 2;    // 0..1 : 64-row group
  const int wu = wv & 3;     // 0..3 : 16-unit group
  const int l15 = lane & 15;
  const int l4 = lane >> 4;
  // ---- XCD-aware decode: 256 blocks, xcd = bid%8 owns 2 ut4 (128 units) ----
  const int bid = blockIdx.x;          // 0..255
  const int xcd = bid & 7;
  const int idx = bid >> 3;            // 0..31 within XCD
  const int role1 = idx >> 4;          // 0 = L0, 1 = L1
  const int rem = idx & 15;
  const int ut4 = xcd * 2 + (rem >> 3);  // 0..15 : 64-unit tile
  const int gy = rem & 7;              // batch group
  const int u0 = ut4 * 64;
  const int m0 = gy * 128;
  const int srow = lane >> 3;
  const int swseg = ((lane & 7) * 16) ^ (srow * 16);  // source-side LDS swizzle
  const long SL0 = 1024l * 1280, SL1 = 1024l * 2048;

  float cst[16];
#pragma unroll
  for (int i = 0; i < 16; ++i) cst[i] = 0.f;

  for (int s = 0; s < 79; ++s) {
    // ---- dependency wait (wave-0 lanes poll producer cells) ----
    unsigned* WA = nullptr;
    unsigned* WB = nullptr;
    if (!role1) {
      if (s >= 1) WA = fset(flags, 0, s - 1, gy);
      if (s >= 3) WB = fset(flags, 1, s - 3, gy);   // slack-3 anti-dep
    } else {
      WA = fset(flags, 0, s, gy);
      if (s >= 1) WB = fset(flags, 1, s - 1, gy);
    }
    if (WA || WB) {
      if (tid < 32) {
        unsigned* p = (tid < 16) ? (WA ? WA + tid : nullptr)
                                 : (WB ? WB + (tid - 16) : nullptr);
        if (p) {
          while (__hip_atomic_load(p, __ATOMIC_RELAXED,
                                   __HIP_MEMORY_SCOPE_AGENT) == 0u)
            __builtin_amdgcn_s_sleep(1);
          (void)__hip_atomic_load(p, __ATOMIC_ACQUIRE, __HIP_MEMORY_SCOPE_AGENT);
        }
      }
      __syncthreads();
    }

    // ---- step params (3-slot rotation) ----
    const int enc = (s < 32) ? 1 : 0;
    const int t = enc ? s : s - 32;          // dec t = 0..46
    const int cur = t % 3, nxt = (t + 1) % 3;
    const short* A; const short* Wt; const float* bs; int ktot;
    short *d1 = nullptr, *d2 = nullptr, *d3 = nullptr, *xq = nullptr;
    int s1 = 0, o1 = 0, xs = 0;
    const short* xe = nullptr; const int* tk = nullptr;
    if (!role1) {
      if (enc) {
        A = xe0 + cur * SL0; Wt = wc_e0; bs = eb0; ktot = 1280;
        d2 = xe1 + cur * SL1;                 // h0(t) -> enc L1 input x-half
        s1 = 1280; o1 = 256; xs = 1280;
        if (t < 31) { d1 = xe0 + nxt * SL0; xq = d1; xe = embe; tk = src + (t + 1) * 1024; }
        else        { d1 = xd0;             xq = xd0; xe = embd; tk = tgt; }  // -> dec slot 0
      } else {
        A = xd0 + cur * SL0; Wt = wc_d0; bs = db0; ktot = 1280;
        d1 = xd0 + nxt * SL0; s1 = 1280; o1 = 256;
        d2 = xd1 + cur * SL1;                 // h0 -> dec L1 input x-half
        if (t < 46) { xq = xd0 + nxt * SL0; xs = 1280; xe = embd; tk = tgt + (t + 1) * 1024; }
      }
    } else {
      if (enc) {
        A = xe1 + cur * SL1; Wt = wc_e1; bs = eb1; ktot = 2048;
        d1 = (t < 31) ? (xe1 + nxt * SL1) : xd1; s1 = 2048; o1 = 1024;  // -> dec slot 0
      } else {
        A = xd1 + cur * SL1; Wt = wc_d1; bs = db1; ktot = 2048;
        d1 = xd1 + nxt * SL1; s1 = 2048; o1 = 1024;
        d3 = dh1 + (long)t * 1024 * 1024;     // archive dh1[t] (s=1024,o=0)
      }
    }

    // ---- GEMM: z = A @ W^T; 3-buffer depth-2 counted-vmcnt pipeline ----
    floatx4 acc[4][4];
#pragma unroll
    for (int g = 0; g < 4; ++g)
#pragma unroll
      for (int mi = 0; mi < 4; ++mi) acc[g][mi] = (floatx4){0.f, 0.f, 0.f, 0.f};

    const char* Ab = (const char*)A;
    const char* Wb = (const char*)Wt;
    const long kbytes = (long)ktot * 2;
    const int nkb = ktot >> 6;

    // 48 chunks of 1 KB per buffer: c<16 A (128 rows x 128 B), c>=16 W
    // (256 gate-rows x 128 B). 8 waves x 6 gloads.
    auto stage = [&](int kb, int bufi) {
      const long kboff = (long)kb * 128;
      short* sb = smem + bufi * 24576;
#pragma unroll
      for (int ci = 0; ci < 6; ++ci) {
        const int c = wv * 6 + ci;
        if (c < 16) {  // A: rows c*8..c*8+8
          const int row = c * 8 + srow;
          gload16(Ab + (long)(m0 + row) * kbytes + kboff + swseg, sb + c * 512);
        } else {       // W: 4 gates x 64 units
          const int cw = c - 16;
          const int wr = cw * 8 + srow;                      // 0..255
          const int wrow = (wr >> 6) * 1024 + u0 + (wr & 63);
          gload16(Wb + (long)wrow * kbytes + kboff + swseg,
                  sb + 8192 + cw * 512);
        }
      }
    };

    asm volatile("s_waitcnt vmcnt(0)" ::: "memory");  // isolate counts
    stage(0, 0);
    stage(1, 1);
    for (int kb = 0; kb < nkb; ++kb) {
      if (kb + 1 < nkb)  asm volatile("s_waitcnt vmcnt(6)" ::: "memory");
      else               asm volatile("s_waitcnt vmcnt(0)" ::: "memory");
      __builtin_amdgcn_sched_barrier(0);
      __builtin_amdgcn_s_barrier();        // all waves: buf[kb%3] ready
      __builtin_amdgcn_sched_barrier(0);
      if (kb + 2 < nkb) stage(kb + 2, (kb + 2) % 3);  // WAR-safe: that buf's
                                                      // readers done pre-barrier
      __builtin_amdgcn_sched_barrier(0);
      const short* sb = smem + (kb % 3) * 24576;
#pragma unroll
      for (int k0 = 0; k0 < 64; k0 += 32) {
        short8 fa[4];
        short8 fb[4];
#pragma unroll
        for (int mi = 0; mi < 4; ++mi) {
          const int r = wm * 64 + mi * 16 + l15;
          fa[mi] = *(const short8*)(sb + r * 64 + ((k0 + l4 * 8) ^ ((r & 7) << 3)));
        }
#pragma unroll
        for (int g = 0; g < 4; ++g) {
          const int r = g * 64 + wu * 16 + l15;
          fb[g] = *(const short8*)(sb + 8192 + r * 64 +
                                   ((k0 + l4 * 8) ^ ((r & 7) << 3)));
        }
#pragma unroll
        for (int g = 0; g < 4; ++g)
#pragma unroll
          for (int mi = 0; mi < 4; ++mi)
            asm volatile("v_mfma_f32_16x16x32_f16 %0, %1, %2, %0"
                         : "+v"(acc[g][mi])
                         : "v"(fa[mi]), "v"(fb[g]));
      }
    }
    __syncthreads();  // all LDS reads retired before ht overwrites buf0
    asm volatile("s_nop 7\ns_nop 7\ns_nop 7");  // MFMA -> VALU hazard guard

    // ---- LSTM cell (c in regs) -> h into LDS transpose tile ----
    const int u = u0 + wu * 16 + l15;
    const float bi = bs[u];
    const float bf_ = bs[1024 + u];
    const float bg = bs[2048 + u];
    const float bo = bs[3072 + u];
    short* ht = smem;  // [128][72] fp16 (18 KB), overlays buf0
    const int uloc = wu * 16 + l15;
#pragma unroll
    for (int mi = 0; mi < 4; ++mi) {
#pragma unroll
      for (int j = 0; j < 4; ++j) {
        const float zi = acc[0][mi][j] + bi;
        const float zf = acc[1][mi][j] + bf_;
        const float zg = acc[2][mi][j] + bg;
        const float zo = acc[3][mi][j] + bo;
        const float gi = 1.f / (1.f + expf(-zi));
        const float gf = 1.f / (1.f + expf(-zf));
        const float gg = tanhf(zg);
        const float go = 1.f / (1.f + expf(-zo));
        const float cn = gf * cst[mi * 4 + j] + gi * gg;
        cst[mi * 4 + j] = cn;
        const int rl = wm * 64 + mi * 16 + l4 * 4 + j;
        ht[rl * 72 + uloc] = f2h(go * tanhf(cn));
      }
    }
    __syncthreads();

    // ---- coalesced h writes (32 B/thread per dest; 64 cols per block) ----
    {
      const int rl = tid >> 2;
      const int seg = (tid & 3) * 16;
      const short8 v0 = *(const short8*)(ht + rl * 72 + seg);
      const short8 v1 = *(const short8*)(ht + rl * 72 + seg + 8);
      const long col = u0 + seg;
      if (d1) {
        short* p = d1 + (long)(m0 + rl) * s1 + o1 + col;
        *(short8*)p = v0; *(short8*)(p + 8) = v1;
      }
      if (d2) {
        short* p = d2 + (long)(m0 + rl) * 2048 + col;
        *(short8*)p = v0; *(short8*)(p + 8) = v1;
      }
      if (d3) {
        short* p = d3 + (long)(m0 + rl) * 1024 + col;
        *(short8*)p = v0; *(short8*)(p + 8) = v1;
      }
    }
    // ---- next-step embedding gather: 256-item slice per L0 block ----
    if (xq && tid < 256) {
      const int i = ut4 * 256 + tid;
      const int row = i >> 5;
      const int e8 = (i & 31) * 8;
      const int b = m0 + row;
      const int tok = tk[b];
      const short8 v = *(const short8*)(xe + (long)tok * 256 + e8);
      *(short8*)(xq + (long)b * xs + e8) = v;
    }

    // ---- publish: all stores drained (syncthreads), then release flag ----
    __syncthreads();
    if (tid == 0)
      __hip_atomic_store(fset(flags, role1, s, gy) + ut4, 1u,
                         __ATOMIC_RELEASE, __HIP_MEMORY_SCOPE_AGENT);
  }
}

// fc projection: out[1:] = dh1_all @ fcWt^T + fc_b
__global__ __launch_bounds__(256) void fc_kernel(
    const short* __restrict__ A, const short* __restrict__ W,
    const float* __restrict__ bias, float* __restrict__ outp) {
  __shared__ short smem[32768];
  const int tid = threadIdx.x;
  const int lane = tid & 63;
  const int wv = tid >> 6;
  const int wm = wv >> 1;
  const int wu = wv & 1;
  const int l15 = lane & 15;
  const int l4 = lane >> 4;
  const int u0 = blockIdx.x * 128;
  const int m0 = blockIdx.y * 128;
  const int srow = lane >> 3;
  const int swseg = ((lane & 7) * 16) ^ (srow * 16);

  floatx4 acc[4][4];
#pragma unroll
  for (int g = 0; g < 4; ++g)
#pragma unroll
    for (int mi = 0; mi < 4; ++mi) acc[g][mi] = (floatx4){0.f, 0.f, 0.f, 0.f};

  const char* Ab = (const char*)A;
  const char* Wb = (const char*)W;
  const long kbytes = 2048;
  const int nkb = 16;

  auto stage = [&](int kb, int bufi) {
    const long kboff = (long)kb * 128;
    short* sb = smem + bufi * 16384;
#pragma unroll
    for (int ci = 0; ci < 8; ++ci) {
      const int c = wv * 8 + ci;
      void* lds = (void*)(sb + c * 512);
      if (c < 16) {
        const int row = c * 8 + srow;
        gload16(Ab + (long)(m0 + row) * kbytes + kboff + swseg, lds);
      } else {
        const int cb = c - 16;
        const int wrow = (cb >> 2) * 32 + u0 + (cb & 3) * 8 + srow;
        gload16(Wb + (long)wrow * kbytes + kboff + swseg, lds);
      }
    }
  };

  stage(0, 0);
  __syncthreads();
  int buf = 0;
  for (int kb = 0; kb < nkb; ++kb) {
    if (kb + 1 < nkb) stage(kb + 1, buf ^ 1);
    const short* sb = smem + buf * 16384;
#pragma unroll
    for (int k0 = 0; k0 < 64; k0 += 32) {
      short8 fa[4];
      short8 fb[4];
#pragma unroll
      for (int mi = 0; mi < 4; ++mi) {
        const int r = wm * 64 + mi * 16 + l15;
        fa[mi] = *(const short8*)(sb + r * 64 + ((k0 + l4 * 8) ^ ((r & 7) << 3)));
      }
      {
        const int r = wu * 16 + l15;
        const int kk = (k0 + l4 * 8) ^ ((r & 7) << 3);
#pragma unroll
        for (int g = 0; g < 4; ++g)
          fb[g] = *(const short8*)(sb + 8192 + (g * 32 + r) * 64 + kk);
      }
#pragma unroll
      for (int g = 0; g < 4; ++g)
#pragma unroll
        for (int mi = 0; mi < 4; ++mi)
          asm volatile("v_mfma_f32_16x16x32_f16 %0, %1, %2, %0"
                       : "+v"(acc[g][mi])
                       : "v"(fa[mi]), "v"(fb[g]));
    }
    __syncthreads();
    buf ^= 1;
  }
  asm volatile("s_nop 7\ns_nop 7\ns_nop 7");

#pragma unroll
  for (int g = 0; g < 4; ++g) {
    const int n = u0 + g * 32 + wu * 16 + l15;
    const float bb = bias[n];
#pragma unroll
    for (int mi = 0; mi < 4; ++mi) {
#pragma unroll
      for (int j = 0; j < 4; ++j) {
        const int r = m0 + wm * 64 + mi * 16 + l4 * 4 + j;
        outp[(long)r * 256 + n] = acc[g][mi][j] + bb;
      }
    }
  }
}

// weights -> fp16, [Wih | Whh] concat along K, gate-major rows, LINEAR layout
__global__ void wprep(const float* __restrict__ A, const float* __restrict__ B,
                      short* __restrict__ dst, int N, int Ka, int Kb) {
  const int ktot = Ka + Kb;
  const int n8 = ktot >> 3;
  const int total = N * n8;
  for (int idx = blockIdx.x * 256 + threadIdx.x; idx < total; idx += gridDim.x * 256) {
    const int n = idx / n8;
    const int k = (idx - n * n8) * 8;
    const float* s = (k < Ka) ? (A + (long)n * Ka + k) : (B + (long)n * Kb + (k - Ka));
    short8 v;
#pragma unroll
    for (int j = 0; j < 8; ++j) v[j] = f2h(s[j]);
    *(short8*)(dst + (long)n * ktot + k) = v;
  }
}

__global__ void embprep(const float* __restrict__ s, short* __restrict__ d, int total8) {
  const int idx = blockIdx.x * 256 + threadIdx.x;
  if (idx >= total8) return;
  short8 v;
#pragma unroll
  for (int j = 0; j < 8; ++j) v[j] = f2h(s[idx * 8 + j]);
  *(short8*)(d + idx * 8) = v;
}

// fc_W [1024][256] -> fcWt [256][1024] fp16, LINEAR
__global__ void fcwprep(const float* __restrict__ fcW, short* __restrict__ dst) {
  const int idx = blockIdx.x * 256 + threadIdx.x;  // 32768
  const int v = idx & 255;
  const int h = (idx >> 8) * 8;
  short8 o;
#pragma unroll
  for (int j = 0; j < 8; ++j) o[j] = f2h(fcW[(long)(h + j) * 256 + v]);
  *(short8*)(dst + (long)v * 1024 + h) = o;
}

// xe0 slot0: x = enc_emb[src[0]], h = 0 ; xe1 slot0 h-half = 0   (LINEAR)
__global__ void initk(const int* __restrict__ src, const float* __restrict__ emb,
                      short* __restrict__ xe0, short* __restrict__ xe1) {
  const int idx = blockIdx.x * 256 + threadIdx.x;
  if (idx < 1024 * 160) {
    const int b = idx / 160;
    const int k = (idx - b * 160) * 8;
    short8 v;
    if (k < 256) {
      const int tok = src[b];
#pragma unroll
      for (int j = 0; j < 8; ++j) v[j] = f2h(emb[(long)tok * 256 + k + j]);
    } else {
#pragma unroll
      for (int j = 0; j < 8; ++j) v[j] = 0;
    }
    *(short8*)(xe0 + (long)b * 1280 + k) = v;
  } else {
    const int i = idx - 1024 * 160;
    if (i < 1024 * 128) {
      const int b = i >> 7;
      const int k = 1024 + (i & 127) * 8;
      short8 v;
#pragma unroll
      for (int j = 0; j < 8; ++j) v[j] = 0;
      *(short8*)(xe1 + (long)b * 2048 + k) = v;
    }
  }
}

extern "C" void kernel_launch(void* const* d_in, const int* in_sizes, int n_in,
                              void* d_out, int out_size, void* d_ws, size_t ws_size,
                              hipStream_t stream) {
  (void)in_sizes; (void)n_in; (void)out_size; (void)ws_size;
  const int* src = (const int*)d_in[0];
  const int* tgt = (const int*)d_in[1];
  const float* enc_emb = (const float*)d_in[2];
  const float* eW0i = (const float*)d_in[3];
  const float* eW0h = (const float*)d_in[4];
  const float* eb0 = (const float*)d_in[5];
  const float* eW1i = (const float*)d_in[6];
  const float* eW1h = (const float*)d_in[7];
  const float* eb1 = (const float*)d_in[8];
  const float* dec_emb = (const float*)d_in[9];
  const float* dW0i = (const float*)d_in[10];
  const float* dW0h = (const float*)d_in[11];
  const float* db0 = (const float*)d_in[12];
  const float* dW1i = (const float*)d_in[13];
  const float* dW1h = (const float*)d_in[14];
  const float* db1 = (const float*)d_in[15];
  const float* fcW = (const float*)d_in[16];
  const float* fcb = (const float*)d_in[17];
  float* out = (float*)d_out;

  char* ws = (char*)d_ws;
  size_t off = 0;
  auto carve = [&](size_t bytes) {
    void* p = ws + off;
    off += (bytes + 255) & ~(size_t)255;
    return p;
  };
  short* wc_e0 = (short*)carve(4096l * 1280 * 2);
  short* wc_e1 = (short*)carve(4096l * 2048 * 2);
  short* wc_d0 = (short*)carve(4096l * 1280 * 2);
  short* wc_d1 = (short*)carve(4096l * 2048 * 2);
  short* fcwt = (short*)carve(256l * 1024 * 2);
  short* embe = (short*)carve(256l * 256 * 2);
  short* embd = (short*)carve(256l * 256 * 2);
  short* xe0 = (short*)carve(3l * 1024 * 1280 * 2);   // 3 slots (slack-3)
  short* xe1 = (short*)carve(3l * 1024 * 2048 * 2);
  short* xd0 = (short*)carve(3l * 1024 * 1280 * 2);
  short* xd1 = (short*)carve(3l * 1024 * 2048 * 2);
  short* dh1 = (short*)carve(47l * 1024 * 1024 * 2);
  const size_t flagbytes = 2l * 79 * 8 * 16 * 4;
  unsigned* flags = (unsigned*)carve(flagbytes);

  hipMemsetAsync(flags, 0, flagbytes, stream);
  hipMemsetAsync(out, 0, 1024l * 256 * 4, stream);  // outputs[0] stays zeros

  wprep<<<2560, 256, 0, stream>>>(eW0i, eW0h, wc_e0, 4096, 256, 1024);
  wprep<<<4096, 256, 0, stream>>>(eW1i, eW1h, wc_e1, 4096, 1024, 1024);
  wprep<<<2560, 256, 0, stream>>>(dW0i, dW0h, wc_d0, 4096, 256, 1024);
  wprep<<<4096, 256, 0, stream>>>(dW1i, dW1h, wc_d1, 4096, 1024, 1024);
  embprep<<<32, 256, 0, stream>>>(enc_emb, embe, 8192);
  embprep<<<32, 256, 0, stream>>>(dec_emb, embd, 8192);
  fcwprep<<<128, 256, 0, stream>>>(fcW, fcwt);
  initk<<<1152, 256, 0, stream>>>(src, enc_emb, xe0, xe1);

  static bool attr_set = false;
  if (!attr_set) {
    hipFuncSetAttribute((const void*)pers_kernel,
                        hipFuncAttributeMaxDynamicSharedMemorySize, 147456);
    attr_set = true;
  }
  pers_kernel<<<256, 512, 147456, stream>>>(
      xe0, xe1, xd0, xd1, wc_e0, wc_e1, wc_d0, wc_d1,
      eb0, eb1, db0, db1, embe, embd, src, tgt, dh1, flags);

  fc_kernel<<<dim3(2, 376), 256, 0, stream>>>(dh1, fcwt, fcb, out + 1024l * 256);
}

// Round 14
// 3656.409 us; speedup vs baseline: 1.3769x; 1.0369x over previous
//
#include <hip/hip_runtime.h>
#include <hip/hip_fp16.h>

typedef __attribute__((ext_vector_type(8))) short short8;
typedef __attribute__((ext_vector_type(4))) float floatx4;

#define DEVFN static __device__ __forceinline__

DEVFN short f2h(float v) { return __half_as_short(__float2half(v)); }

DEVFN void gload16(const void* g, void* l) {
  void* gnc = const_cast<void*>(g);
  __builtin_amdgcn_global_load_lds(
      (__attribute__((address_space(1))) void*)gnc,
      (__attribute__((address_space(3))) void*)l, 16, 0, 0);
}

// flag set for (role, s, gy): 16 cells, one per 64-unit block
DEVFN unsigned* fset(unsigned* f, int role, int s, int gy) {
  return f + ((((role * 79) + s) * 8 + gy) << 4);
}

// Persistent dataflow kernel, slack-3 (slot = t%3):
//   L0(s) <- L0(s-1), L1(s-3);   L1(s) <- L0(s), L1(s-1)
// Block = 64 units x 128 rows, 1024 thr = 16 waves (wave tile 32r x 16u,
// acc[4][2]) -> 16 waves/CU (4/SIMD)  [R12's TLP]  combined with
// K=64, THREE 48 KB LDS buffers, prefetch depth 2, counted vmcnt(3) +
// raw s_barrier  [R13's pipeline].
// T1: XCD owns a 128-unit superblock -> W set 3.4 MB < 4 MB L2.
__global__ __launch_bounds__(1024, 4) void pers_kernel(
    short* xe0, short* xe1, short* xd0, short* xd1,
    const short* wc_e0, const short* wc_e1, const short* wc_d0, const short* wc_d1,
    const float* eb0, const float* eb1, const float* db0, const float* db1,
    const short* embe, const short* embd,
    const int* __restrict__ src, const int* __restrict__ tgt,
    short* dh1, unsigned* flags) {
  extern __shared__ short smem[];  // 3 x 24576 shorts (48 KB: A 16K | W 32K)
  const int tid = threadIdx.x;
  const int lane = tid & 63;
  const int wv = tid >> 6;   // 0..15
  const int wm = wv >> 2;    // 0..3 : 32-row group
  const int wu = wv & 3;     // 0..3 : 16-unit group
  const int l15 = lane & 15;
  const int l4 = lane >> 4;
  // ---- XCD-aware decode: 256 blocks, xcd = bid%8 owns 2 ut4 (128 units) ----
  const int bid = blockIdx.x;          // 0..255
  const int xcd = bid & 7;
  const int idx = bid >> 3;            // 0..31 within XCD
  const int role1 = idx >> 4;          // 0 = L0, 1 = L1
  const int rem = idx & 15;
  const int ut4 = xcd * 2 + (rem >> 3);  // 0..15 : 64-unit tile
  const int gy = rem & 7;              // batch group
  const int u0 = ut4 * 64;
  const int m0 = gy * 128;
  const int srow = lane >> 3;
  const int swseg = ((lane & 7) * 16) ^ (srow * 16);  // source-side LDS swizzle
  const long SL0 = 1024l * 1280, SL1 = 1024l * 2048;

  float cst[8];
#pragma unroll
  for (int i = 0; i < 8; ++i) cst[i] = 0.f;

  for (int s = 0; s < 79; ++s) {
    // ---- dependency wait (wave-0 lanes poll producer cells) ----
    unsigned* WA = nullptr;
    unsigned* WB = nullptr;
    if (!role1) {
      if (s >= 1) WA = fset(flags, 0, s - 1, gy);
      if (s >= 3) WB = fset(flags, 1, s - 3, gy);   // slack-3 anti-dep
    } else {
      WA = fset(flags, 0, s, gy);
      if (s >= 1) WB = fset(flags, 1, s - 1, gy);
    }
    if (WA || WB) {
      if (tid < 32) {
        unsigned* p = (tid < 16) ? (WA ? WA + tid : nullptr)
                                 : (WB ? WB + (tid - 16) : nullptr);
        if (p) {
          while (__hip_atomic_load(p, __ATOMIC_RELAXED,
                                   __HIP_MEMORY_SCOPE_AGENT) == 0u)
            __builtin_amdgcn_s_sleep(1);
          (void)__hip_atomic_load(p, __ATOMIC_ACQUIRE, __HIP_MEMORY_SCOPE_AGENT);
        }
      }
      __syncthreads();
    }

    // ---- step params (3-slot rotation) ----
    const int enc = (s < 32) ? 1 : 0;
    const int t = enc ? s : s - 32;          // dec t = 0..46
    const int cur = t % 3, nxt = (t + 1) % 3;
    const short* A; const short* Wt; const float* bs; int ktot;
    short *d1 = nullptr, *d2 = nullptr, *d3 = nullptr, *xq = nullptr;
    int s1 = 0, o1 = 0, xs = 0;
    const short* xe = nullptr; const int* tk = nullptr;
    if (!role1) {
      if (enc) {
        A = xe0 + cur * SL0; Wt = wc_e0; bs = eb0; ktot = 1280;
        d2 = xe1 + cur * SL1;                 // h0(t) -> enc L1 input x-half
        s1 = 1280; o1 = 256; xs = 1280;
        if (t < 31) { d1 = xe0 + nxt * SL0; xq = d1; xe = embe; tk = src + (t + 1) * 1024; }
        else        { d1 = xd0;             xq = xd0; xe = embd; tk = tgt; }  // -> dec slot 0
      } else {
        A = xd0 + cur * SL0; Wt = wc_d0; bs = db0; ktot = 1280;
        d1 = xd0 + nxt * SL0; s1 = 1280; o1 = 256;
        d2 = xd1 + cur * SL1;                 // h0 -> dec L1 input x-half
        if (t < 46) { xq = xd0 + nxt * SL0; xs = 1280; xe = embd; tk = tgt + (t + 1) * 1024; }
      }
    } else {
      if (enc) {
        A = xe1 + cur * SL1; Wt = wc_e1; bs = eb1; ktot = 2048;
        d1 = (t < 31) ? (xe1 + nxt * SL1) : xd1; s1 = 2048; o1 = 1024;  // -> dec slot 0
      } else {
        A = xd1 + cur * SL1; Wt = wc_d1; bs = db1; ktot = 2048;
        d1 = xd1 + nxt * SL1; s1 = 2048; o1 = 1024;
        d3 = dh1 + (long)t * 1024 * 1024;     // archive dh1[t] (s=1024,o=0)
      }
    }

    // ---- GEMM: z = A @ W^T; 3-buffer depth-2 counted-vmcnt pipeline ----
    floatx4 acc[4][2];
#pragma unroll
    for (int g = 0; g < 4; ++g)
#pragma unroll
      for (int mi = 0; mi < 2; ++mi) acc[g][mi] = (floatx4){0.f, 0.f, 0.f, 0.f};

    const char* Ab = (const char*)A;
    const char* Wb = (const char*)Wt;
    const long kbytes = (long)ktot * 2;
    const int nkb = ktot >> 6;

    // 48 chunks of 1 KB per buffer: c<16 A (128 rows x 128 B), c>=16 W
    // (256 gate-rows x 128 B). 16 waves x 3 gloads.
    auto stage = [&](int kb, int bufi) {
      const long kboff = (long)kb * 128;
      short* sb = smem + bufi * 24576;
#pragma unroll
      for (int ci = 0; ci < 3; ++ci) {
        const int c = wv * 3 + ci;
        if (c < 16) {  // A: rows c*8..c*8+8
          const int row = c * 8 + srow;
          gload16(Ab + (long)(m0 + row) * kbytes + kboff + swseg, sb + c * 512);
        } else {       // W: 4 gates x 64 units
          const int cw = c - 16;
          const int wr = cw * 8 + srow;                      // 0..255
          const int wrow = (wr >> 6) * 1024 + u0 + (wr & 63);
          gload16(Wb + (long)wrow * kbytes + kboff + swseg,
                  sb + 8192 + cw * 512);
        }
      }
    };

    asm volatile("s_waitcnt vmcnt(0)" ::: "memory");  // isolate counts
    stage(0, 0);
    stage(1, 1);
    for (int kb = 0; kb < nkb; ++kb) {
      if (kb + 1 < nkb)  asm volatile("s_waitcnt vmcnt(3)" ::: "memory");
      else               asm volatile("s_waitcnt vmcnt(0)" ::: "memory");
      __builtin_amdgcn_sched_barrier(0);
      __builtin_amdgcn_s_barrier();        // all waves: buf[kb%3] ready
      __builtin_amdgcn_sched_barrier(0);
      if (kb + 2 < nkb) stage(kb + 2, (kb + 2) % 3);  // WAR-safe: that buf's
                                                      // readers done pre-barrier
      __builtin_amdgcn_sched_barrier(0);
      const short* sb = smem + (kb % 3) * 24576;
#pragma unroll
      for (int k0 = 0; k0 < 64; k0 += 32) {
        short8 fa[2];
        short8 fb[4];
#pragma unroll
        for (int mi = 0; mi < 2; ++mi) {
          const int r = wm * 32 + mi * 16 + l15;
          fa[mi] = *(const short8*)(sb + r * 64 + ((k0 + l4 * 8) ^ ((r & 7) << 3)));
        }
#pragma unroll
        for (int g = 0; g < 4; ++g) {
          const int r = g * 64 + wu * 16 + l15;
          fb[g] = *(const short8*)(sb + 8192 + r * 64 +
                                   ((k0 + l4 * 8) ^ ((r & 7) << 3)));
        }
#pragma unroll
        for (int g = 0; g < 4; ++g)
#pragma unroll
          for (int mi = 0; mi < 2; ++mi)
            asm volatile("v_mfma_f32_16x16x32_f16 %0, %1, %2, %0"
                         : "+v"(acc[g][mi])
                         : "v"(fa[mi]), "v"(fb[g]));
      }
    }
    __syncthreads();  // all LDS reads retired before ht overwrites buf0
    asm volatile("s_nop 7\ns_nop 7\ns_nop 7");  // MFMA -> VALU hazard guard

    // ---- LSTM cell (c in regs) -> h into LDS transpose tile ----
    const int u = u0 + wu * 16 + l15;
    const float bi = bs[u];
    const float bf_ = bs[1024 + u];
    const float bg = bs[2048 + u];
    const float bo = bs[3072 + u];
    short* ht = smem;  // [128][72] fp16 (18 KB), overlays buf0
    const int uloc = wu * 16 + l15;
#pragma unroll
    for (int mi = 0; mi < 2; ++mi) {
#pragma unroll
      for (int j = 0; j < 4; ++j) {
        const float zi = acc[0][mi][j] + bi;
        const float zf = acc[1][mi][j] + bf_;
        const float zg = acc[2][mi][j] + bg;
        const float zo = acc[3][mi][j] + bo;
        const float gi = 1.f / (1.f + expf(-zi));
        const float gf = 1.f / (1.f + expf(-zf));
        const float gg = tanhf(zg);
        const float go = 1.f / (1.f + expf(-zo));
        const float cn = gf * cst[mi * 4 + j] + gi * gg;
        cst[mi * 4 + j] = cn;
        const int rl = wm * 32 + mi * 16 + l4 * 4 + j;
        ht[rl * 72 + uloc] = f2h(go * tanhf(cn));
      }
    }
    __syncthreads();

    // ---- coalesced h writes (16 B/thread per dest; 64 cols per block) ----
    {
      const int rl = tid >> 3;          // 0..127
      const int seg = (tid & 7) * 8;    // 0..56
      const short8 v = *(const short8*)(ht + rl * 72 + seg);
      const long col = u0 + seg;
      if (d1) *(short8*)(d1 + (long)(m0 + rl) * s1 + o1 + col) = v;
      if (d2) *(short8*)(d2 + (long)(m0 + rl) * 2048 + col) = v;
      if (d3) *(short8*)(d3 + (long)(m0 + rl) * 1024 + col) = v;
    }
    // ---- next-step embedding gather: 256-item slice per L0 block ----
    if (xq && tid < 256) {
      const int i = ut4 * 256 + tid;
      const int row = i >> 5;
      const int e8 = (i & 31) * 8;
      const int b = m0 + row;
      const int tok = tk[b];
      const short8 v = *(const short8*)(xe + (long)tok * 256 + e8);
      *(short8*)(xq + (long)b * xs + e8) = v;
    }

    // ---- publish: all stores drained (syncthreads), then release flag ----
    __syncthreads();
    if (tid == 0)
      __hip_atomic_store(fset(flags, role1, s, gy) + ut4, 1u,
                         __ATOMIC_RELEASE, __HIP_MEMORY_SCOPE_AGENT);
  }
}

// fc projection: out[1:] = dh1_all @ fcWt^T + fc_b
__global__ __launch_bounds__(256) void fc_kernel(
    const short* __restrict__ A, const short* __restrict__ W,
    const float* __restrict__ bias, float* __restrict__ outp) {
  __shared__ short smem[32768];
  const int tid = threadIdx.x;
  const int lane = tid & 63;
  const int wv = tid >> 6;
  const int wm = wv >> 1;
  const int wu = wv & 1;
  const int l15 = lane & 15;
  const int l4 = lane >> 4;
  const int u0 = blockIdx.x * 128;
  const int m0 = blockIdx.y * 128;
  const int srow = lane >> 3;
  const int swseg = ((lane & 7) * 16) ^ (srow * 16);

  floatx4 acc[4][4];
#pragma unroll
  for (int g = 0; g < 4; ++g)
#pragma unroll
    for (int mi = 0; mi < 4; ++mi) acc[g][mi] = (floatx4){0.f, 0.f, 0.f, 0.f};

  const char* Ab = (const char*)A;
  const char* Wb = (const char*)W;
  const long kbytes = 2048;
  const int nkb = 16;

  auto stage = [&](int kb, int bufi) {
    const long kboff = (long)kb * 128;
    short* sb = smem + bufi * 16384;
#pragma unroll
    for (int ci = 0; ci < 8; ++ci) {
      const int c = wv * 8 + ci;
      void* lds = (void*)(sb + c * 512);
      if (c < 16) {
        const int row = c * 8 + srow;
        gload16(Ab + (long)(m0 + row) * kbytes + kboff + swseg, lds);
      } else {
        const int cb = c - 16;
        const int wrow = (cb >> 2) * 32 + u0 + (cb & 3) * 8 + srow;
        gload16(Wb + (long)wrow * kbytes + kboff + swseg, lds);
      }
    }
  };

  stage(0, 0);
  __syncthreads();
  int buf = 0;
  for (int kb = 0; kb < nkb; ++kb) {
    if (kb + 1 < nkb) stage(kb + 1, buf ^ 1);
    const short* sb = smem + buf * 16384;
#pragma unroll
    for (int k0 = 0; k0 < 64; k0 += 32) {
      short8 fa[4];
      short8 fb[4];
#pragma unroll
      for (int mi = 0; mi < 4; ++mi) {
        const int r = wm * 64 + mi * 16 + l15;
        fa[mi] = *(const short8*)(sb + r * 64 + ((k0 + l4 * 8) ^ ((r & 7) << 3)));
      }
      {
        const int r = wu * 16 + l15;
        const int kk = (k0 + l4 * 8) ^ ((r & 7) << 3);
#pragma unroll
        for (int g = 0; g < 4; ++g)
          fb[g] = *(const short8*)(sb + 8192 + (g * 32 + r) * 64 + kk);
      }
#pragma unroll
      for (int g = 0; g < 4; ++g)
#pragma unroll
        for (int mi = 0; mi < 4; ++mi)
          asm volatile("v_mfma_f32_16x16x32_f16 %0, %1, %2, %0"
                       : "+v"(acc[g][mi])
                       : "v"(fa[mi]), "v"(fb[g]));
    }
    __syncthreads();
    buf ^= 1;
  }
  asm volatile("s_nop 7\ns_nop 7\ns_nop 7");

#pragma unroll
  for (int g = 0; g < 4; ++g) {
    const int n = u0 + g * 32 + wu * 16 + l15;
    const float bb = bias[n];
#pragma unroll
    for (int mi = 0; mi < 4; ++mi) {
#pragma unroll
      for (int j = 0; j < 4; ++j) {
        const int r = m0 + wm * 64 + mi * 16 + l4 * 4 + j;
        outp[(long)r * 256 + n] = acc[g][mi][j] + bb;
      }
    }
  }
}

// weights -> fp16, [Wih | Whh] concat along K, gate-major rows, LINEAR layout
__global__ void wprep(const float* __restrict__ A, const float* __restrict__ B,
                      short* __restrict__ dst, int N, int Ka, int Kb) {
  const int ktot = Ka + Kb;
  const int n8 = ktot >> 3;
  const int total = N * n8;
  for (int idx = blockIdx.x * 256 + threadIdx.x; idx < total; idx += gridDim.x * 256) {
    const int n = idx / n8;
    const int k = (idx - n * n8) * 8;
    const float* s = (k < Ka) ? (A + (long)n * Ka + k) : (B + (long)n * Kb + (k - Ka));
    short8 v;
#pragma unroll
    for (int j = 0; j < 8; ++j) v[j] = f2h(s[j]);
    *(short8*)(dst + (long)n * ktot + k) = v;
  }
}

__global__ void embprep(const float* __restrict__ s, short* __restrict__ d, int total8) {
  const int idx = blockIdx.x * 256 + threadIdx.x;
  if (idx >= total8) return;
  short8 v;
#pragma unroll
  for (int j = 0; j < 8; ++j) v[j] = f2h(s[idx * 8 + j]);
  *(short8*)(d + idx * 8) = v;
}

// fc_W [1024][256] -> fcWt [256][1024] fp16, LINEAR
__global__ void fcwprep(const float* __restrict__ fcW, short* __restrict__ dst) {
  const int idx = blockIdx.x * 256 + threadIdx.x;  // 32768
  const int v = idx & 255;
  const int h = (idx >> 8) * 8;
  short8 o;
#pragma unroll
  for (int j = 0; j < 8; ++j) o[j] = f2h(fcW[(long)(h + j) * 256 + v]);
  *(short8*)(dst + (long)v * 1024 + h) = o;
}

// xe0 slot0: x = enc_emb[src[0]], h = 0 ; xe1 slot0 h-half = 0   (LINEAR)
__global__ void initk(const int* __restrict__ src, const float* __restrict__ emb,
                      short* __restrict__ xe0, short* __restrict__ xe1) {
  const int idx = blockIdx.x * 256 + threadIdx.x;
  if (idx < 1024 * 160) {
    const int b = idx / 160;
    const int k = (idx - b * 160) * 8;
    short8 v;
    if (k < 256) {
      const int tok = src[b];
#pragma unroll
      for (int j = 0; j < 8; ++j) v[j] = f2h(emb[(long)tok * 256 + k + j]);
    } else {
#pragma unroll
      for (int j = 0; j < 8; ++j) v[j] = 0;
    }
    *(short8*)(xe0 + (long)b * 1280 + k) = v;
  } else {
    const int i = idx - 1024 * 160;
    if (i < 1024 * 128) {
      const int b = i >> 7;
      const int k = 1024 + (i & 127) * 8;
      short8 v;
#pragma unroll
      for (int j = 0; j < 8; ++j) v[j] = 0;
      *(short8*)(xe1 + (long)b * 2048 + k) = v;
    }
  }
}

extern "C" void kernel_launch(void* const* d_in, const int* in_sizes, int n_in,
                              void* d_out, int out_size, void* d_ws, size_t ws_size,
                              hipStream_t stream) {
  (void)in_sizes; (void)n_in; (void)out_size; (void)ws_size;
  const int* src = (const int*)d_in[0];
  const int* tgt = (const int*)d_in[1];
  const float* enc_emb = (const float*)d_in[2];
  const float* eW0i = (const float*)d_in[3];
  const float* eW0h = (const float*)d_in[4];
  const float* eb0 = (const float*)d_in[5];
  const float* eW1i = (const float*)d_in[6];
  const float* eW1h = (const float*)d_in[7];
  const float* eb1 = (const float*)d_in[8];
  const float* dec_emb = (const float*)d_in[9];
  const float* dW0i = (const float*)d_in[10];
  const float* dW0h = (const float*)d_in[11];
  const float* db0 = (const float*)d_in[12];
  const float* dW1i = (const float*)d_in[13];
  const float* dW1h = (const float*)d_in[14];
  const float* db1 = (const float*)d_in[15];
  const float* fcW = (const float*)d_in[16];
  const float* fcb = (const float*)d_in[17];
  float* out = (float*)d_out;

  char* ws = (char*)d_ws;
  size_t off = 0;
  auto carve = [&](size_t bytes) {
    void* p = ws + off;
    off += (bytes + 255) & ~(size_t)255;
    return p;
  };
  short* wc_e0 = (short*)carve(4096l * 1280 * 2);
  short* wc_e1 = (short*)carve(4096l * 2048 * 2);
  short* wc_d0 = (short*)carve(4096l * 1280 * 2);
  short* wc_d1 = (short*)carve(4096l * 2048 * 2);
  short* fcwt = (short*)carve(256l * 1024 * 2);
  short* embe = (short*)carve(256l * 256 * 2);
  short* embd = (short*)carve(256l * 256 * 2);
  short* xe0 = (short*)carve(3l * 1024 * 1280 * 2);   // 3 slots (slack-3)
  short* xe1 = (short*)carve(3l * 1024 * 2048 * 2);
  short* xd0 = (short*)carve(3l * 1024 * 1280 * 2);
  short* xd1 = (short*)carve(3l * 1024 * 2048 * 2);
  short* dh1 = (short*)carve(47l * 1024 * 1024 * 2);
  const size_t flagbytes = 2l * 79 * 8 * 16 * 4;
  unsigned* flags = (unsigned*)carve(flagbytes);

  hipMemsetAsync(flags, 0, flagbytes, stream);
  hipMemsetAsync(out, 0, 1024l * 256 * 4, stream);  // outputs[0] stays zeros

  wprep<<<2560, 256, 0, stream>>>(eW0i, eW0h, wc_e0, 4096, 256, 1024);
  wprep<<<4096, 256, 0, stream>>>(eW1i, eW1h, wc_e1, 4096, 1024, 1024);
  wprep<<<2560, 256, 0, stream>>>(dW0i, dW0h, wc_d0, 4096, 256, 1024);
  wprep<<<4096, 256, 0, stream>>>(dW1i, dW1h, wc_d1, 4096, 1024, 1024);
  embprep<<<32, 256, 0, stream>>>(enc_emb, embe, 8192);
  embprep<<<32, 256, 0, stream>>>(dec_emb, embd, 8192);
  fcwprep<<<128, 256, 0, stream>>>(fcW, fcwt);
  initk<<<1152, 256, 0, stream>>>(src, enc_emb, xe0, xe1);

  static bool attr_set = false;
  if (!attr_set) {
    hipFuncSetAttribute((const void*)pers_kernel,
                        hipFuncAttributeMaxDynamicSharedMemorySize, 147456);
    attr_set = true;
  }
  pers_kernel<<<256, 1024, 147456, stream>>>(
      xe0, xe1, xd0, xd1, wc_e0, wc_e1, wc_d0, wc_d1,
      eb0, eb1, db0, db1, embe, embd, src, tgt, dh1, flags);

  fc_kernel<<<dim3(2, 376), 256, 0, stream>>>(dh1, fcwt, fcb, out + 1024l * 256);
}